// Round 2
// baseline (1120.975 us; speedup 1.0000x reference)
//
#include <hip/hip_runtime.h>
#include <hip/hip_bf16.h>
#include <math.h>

constexpr int N_NODES = 50000;
constexpr int T_STEPS = 25;
constexpr int A_DIM   = 16;
constexpr int H_DIM   = 128;
constexpr int G3      = 3 * H_DIM;   // 384
constexpr int E_EDGES = 800000;
constexpr int I_DIM   = 64;
constexpr float LN_EPS = 1e-5f;
constexpr int NT = (N_NODES + 31) / 32;   // 1563 node tiles of 32
constexpr int NT16 = N_NODES / 16;        // 3125 exact (50000 = 16*3125)

using bf16x8 = __attribute__((ext_vector_type(8))) short;
using f32x4  = __attribute__((ext_vector_type(4))) float;

static __device__ __forceinline__ float sigm(float x) { return 1.f / (1.f + __expf(-x)); }
static __device__ __forceinline__ float tanh_fast(float x) { return 2.f / (1.f + __expf(-2.f * x)) - 1.f; }
static __device__ __forceinline__ float softplus_f(float x) {
    return (x > 20.f) ? x : log1pf(__expf(x));
}
static __device__ __forceinline__ unsigned short f2bf(float f) {
    __hip_bfloat16 b = __float2bfloat16(f);   // RNE
    return *(unsigned short*)&b;
}

// ---------------- graph preprocessing ----------------

__global__ void k_zero(int* deg_out, int* deg_in, int* cursor, int* esrc) {
    for (int i = blockIdx.x * blockDim.x + threadIdx.x; i < E_EDGES; i += gridDim.x * blockDim.x) {
        esrc[i] = 0;
        if (i < N_NODES) { deg_out[i] = 0; deg_in[i] = 0; cursor[i] = 0; }
    }
}

__global__ void k_hist(const int* __restrict__ src, const int* __restrict__ dst,
                       int* __restrict__ deg_out, int* __restrict__ deg_in) {
    for (int e = blockIdx.x * blockDim.x + threadIdx.x; e < E_EDGES; e += gridDim.x * blockDim.x) {
        int s = src[e], d = dst[e];
        if (s >= 0 && s < N_NODES) atomicAdd(&deg_out[s], 1);
        if (d >= 0 && d < N_NODES) atomicAdd(&deg_in[d], 1);
    }
}

__launch_bounds__(1024)
__global__ void k_scan(const int* __restrict__ deg, int* __restrict__ offs) {
    __shared__ int wsum[16];
    __shared__ int carry;
    const int tid = threadIdx.x;
    const int lane = tid & 63, wid = tid >> 6;
    if (tid == 0) carry = 0;
    __syncthreads();
    for (int base = 0; base < N_NODES; base += 1024) {
        int i = base + tid;
        int v = (i < N_NODES) ? deg[i] : 0;
        int x = v;
        #pragma unroll
        for (int off = 1; off < 64; off <<= 1) {
            int yv = __shfl_up(x, off);
            if (lane >= off) x += yv;
        }
        if (lane == 63) wsum[wid] = x;
        __syncthreads();
        if (wid == 0 && lane < 16) {
            int s = wsum[lane];
            #pragma unroll
            for (int off = 1; off < 16; off <<= 1) {
                int yv = __shfl_up(s, off, 16);
                if (lane >= off) s += yv;
            }
            wsum[lane] = s;
        }
        __syncthreads();
        int excl = carry + (wid > 0 ? wsum[wid - 1] : 0) + x - v;
        if (i < N_NODES) offs[i] = excl;
        __syncthreads();
        if (tid == 0) carry += wsum[15];
        __syncthreads();
    }
    if (tid == 0) offs[N_NODES] = carry;
}

__global__ void k_scatter(const int* __restrict__ src, const int* __restrict__ dst,
                          const int* __restrict__ offs, int* __restrict__ cursor,
                          int* __restrict__ esrc) {
    for (int e = blockIdx.x * blockDim.x + threadIdx.x; e < E_EDGES; e += gridDim.x * blockDim.x) {
        int d = dst[e];
        if (d < 0 || d >= N_NODES) continue;
        int pos = offs[d] + atomicAdd(&cursor[d], 1);
        if (pos >= 0 && pos < E_EDGES) esrc[pos] = src[e];
    }
}

// ---------------- GRU via MFMA (grid raised 256 -> NT for 2 blocks/CU occupancy) ----------------
__launch_bounds__(512, 2)
__global__ void k_gru(const float* __restrict__ actions,
                      const float* __restrict__ hidden,
                      const float* __restrict__ W_ih,
                      const float* __restrict__ W_hh,
                      const float* __restrict__ b_ih,
                      const float* __restrict__ b_hh,
                      float* __restrict__ h_out) {
    __shared__ __align__(16) unsigned short sX[32 * 424];      // 27.1 KB
    __shared__ __align__(16) unsigned short sH[2][32 * 152];   // 19.5 KB

    const int tid  = threadIdx.x;
    const int wid  = tid >> 6;
    const int lane = tid & 63;
    const int quad = lane >> 4;
    const int l16  = lane & 15;
    const int mt   = wid & 1;
    const int g    = wid >> 1;

    int tbase[6];
    tbase[0] = (2 * g) * 16;       tbase[1] = (2 * g + 1) * 16;
    tbase[2] = (8 + 2 * g) * 16;   tbase[3] = (9 + 2 * g) * 16;
    tbase[4] = (16 + 2 * g) * 16;  tbase[5] = (17 + 2 * g) * 16;

    bf16x8 Bhh[6][4];
    #pragma unroll
    for (int ti = 0; ti < 6; ++ti) {
        const float* rowp = W_hh + (size_t)(tbase[ti] + l16) * H_DIM;
        #pragma unroll
        for (int kc = 0; kc < 4; ++kc) {
            const float* p = rowp + kc * 32 + quad * 8;
            float4 f0 = *(const float4*)p;
            float4 f1 = *(const float4*)(p + 4);
            bf16x8 v;
            v[0] = f2bf(f0.x); v[1] = f2bf(f0.y); v[2] = f2bf(f0.z); v[3] = f2bf(f0.w);
            v[4] = f2bf(f1.x); v[5] = f2bf(f1.y); v[6] = f2bf(f1.z); v[7] = f2bf(f1.w);
            Bhh[ti][kc] = v;
        }
    }
    bf16x8 Bih[6];
    #pragma unroll
    for (int ti = 0; ti < 6; ++ti) {
        bf16x8 v;
        #pragma unroll
        for (int j = 0; j < 8; ++j) v[j] = 0;
        if (quad < 2) {
            const float* p = W_ih + (size_t)(tbase[ti] + l16) * A_DIM + quad * 8;
            float4 f0 = *(const float4*)p;
            float4 f1 = *(const float4*)(p + 4);
            v[0] = f2bf(f0.x); v[1] = f2bf(f0.y); v[2] = f2bf(f0.z); v[3] = f2bf(f0.w);
            v[4] = f2bf(f1.x); v[5] = f2bf(f1.y); v[6] = f2bf(f1.z); v[7] = f2bf(f1.w);
        }
        Bih[ti] = v;
    }
    float br[2], bz[2], bin_[2], bhn[2];
    #pragma unroll
    for (int t2 = 0; t2 < 2; ++t2) {
        int j = 32 * g + 16 * t2 + l16;
        br[t2]  = b_ih[j] + b_hh[j];
        bz[t2]  = b_ih[H_DIM + j] + b_hh[H_DIM + j];
        bin_[t2] = b_ih[2 * H_DIM + j];
        bhn[t2] = b_hh[2 * H_DIM + j];
    }

    const f32x4 z4 = {0.f, 0.f, 0.f, 0.f};

    for (int tile = blockIdx.x; tile < NT; tile += gridDim.x) {
        const int base = tile * 32;
        for (int idx = tid; idx < 32 * 424; idx += 512) {
            int nl = idx / 424, p = idx - nl * 424;
            int n = base + nl;
            float f = (p < 400 && n < N_NODES) ? actions[(size_t)n * 400 + p] : 0.f;
            sX[nl * 424 + p] = f2bf(f);
        }
        for (int idx = tid; idx < 32 * H_DIM; idx += 512) {
            int nl = idx >> 7, k = idx & 127;
            int n = base + nl;
            sH[0][nl * 152 + k] = f2bf((n < N_NODES) ? hidden[(size_t)n * H_DIM + k] : 0.f);
        }
        float hp[2][4];
        #pragma unroll
        for (int t2 = 0; t2 < 2; ++t2)
            #pragma unroll
            for (int r = 0; r < 4; ++r) {
                int nl = mt * 16 + quad * 4 + r;
                int n = base + nl;
                int j = 32 * g + 16 * t2 + l16;
                hp[t2][r] = (n < N_NODES) ? hidden[(size_t)n * H_DIM + j] : 0.f;
            }
        __syncthreads();

        int cur = 0;
        for (int t = 0; t < T_STEPS; ++t) {
            bf16x8 ax;
            {
                const unsigned short* p = &sX[(mt * 16 + l16) * 424 + t * 16 + quad * 8];
                bf16x8 v = *(const bf16x8*)p;
                if (quad >= 2) {
                    #pragma unroll
                    for (int j = 0; j < 8; ++j) v[j] = 0;
                }
                ax = v;
            }
            bf16x8 ah[4];
            #pragma unroll
            for (int kc = 0; kc < 4; ++kc)
                ah[kc] = *(const bf16x8*)&sH[cur][(mt * 16 + l16) * 152 + kc * 32 + quad * 8];

            f32x4 Cr[2], Cz[2], Cin[2], Chn[2];
            #pragma unroll
            for (int t2 = 0; t2 < 2; ++t2) {
                Cr[t2]  = __builtin_amdgcn_mfma_f32_16x16x32_bf16(ax, Bih[t2],     z4, 0, 0, 0);
                Cz[t2]  = __builtin_amdgcn_mfma_f32_16x16x32_bf16(ax, Bih[2 + t2], z4, 0, 0, 0);
                Cin[t2] = __builtin_amdgcn_mfma_f32_16x16x32_bf16(ax, Bih[4 + t2], z4, 0, 0, 0);
                Chn[t2] = z4;
                #pragma unroll
                for (int kc = 0; kc < 4; ++kc) {
                    Cr[t2]  = __builtin_amdgcn_mfma_f32_16x16x32_bf16(ah[kc], Bhh[t2][kc],     Cr[t2], 0, 0, 0);
                    Cz[t2]  = __builtin_amdgcn_mfma_f32_16x16x32_bf16(ah[kc], Bhh[2 + t2][kc], Cz[t2], 0, 0, 0);
                    Chn[t2] = __builtin_amdgcn_mfma_f32_16x16x32_bf16(ah[kc], Bhh[4 + t2][kc], Chn[t2], 0, 0, 0);
                }
            }
            int nxt = cur ^ 1;
            #pragma unroll
            for (int t2 = 0; t2 < 2; ++t2) {
                #pragma unroll
                for (int r = 0; r < 4; ++r) {
                    float rg = sigm(Cr[t2][r] + br[t2]);
                    float zg = sigm(Cz[t2][r] + bz[t2]);
                    float ng = tanh_fast(Cin[t2][r] + bin_[t2] + rg * (Chn[t2][r] + bhn[t2]));
                    float h2 = ng + zg * (hp[t2][r] - ng);
                    hp[t2][r] = h2;
                    int nl = mt * 16 + quad * 4 + r;
                    int j = 32 * g + 16 * t2 + l16;
                    sH[nxt][nl * 152 + j] = f2bf(h2);
                }
            }
            cur = nxt;
            __syncthreads();
        }
        #pragma unroll
        for (int t2 = 0; t2 < 2; ++t2)
            #pragma unroll
            for (int r = 0; r < 4; ++r) {
                int nl = mt * 16 + quad * 4 + r;
                int n = base + nl;
                if (n < N_NODES) {
                    int j = 32 * g + 16 * t2 + l16;
                    h_out[(size_t)n * H_DIM + j] = hp[t2][r];
                }
            }
        __syncthreads();
    }
}

// ---------------- per-node LN stats packed: pqr[n] = {inv*ns, mu*inv*ns, ns, 0} ----------------
__global__ void k_stats(const float* __restrict__ h, const int* __restrict__ deg_out,
                        float4* __restrict__ pqr) {
    int n = blockIdx.x * (blockDim.x >> 6) + (threadIdx.x >> 6);
    int lane = threadIdx.x & 63;
    if (n >= N_NODES) return;
    float v0 = h[(size_t)n * H_DIM + lane];
    float v1 = h[(size_t)n * H_DIM + 64 + lane];
    float s = v0 + v1, qq = v0 * v0 + v1 * v1;
    #pragma unroll
    for (int m = 32; m; m >>= 1) { s += __shfl_xor(s, m); qq += __shfl_xor(qq, m); }
    float mu = s * (1.f / H_DIM);
    float var = fmaxf(qq * (1.f / H_DIM) - mu * mu, 0.f);
    float inv = rsqrtf(var + LN_EPS);
    int d = deg_out[n];
    float ns = rsqrtf((float)(d > 0 ? d : 1));
    if (lane == 0) pqr[n] = make_float4(inv * ns, mu * inv * ns, ns, 0.f);
}

// ---------------- fold Wg into the 4 heads: W_comb[r][k] = sum_c Wg[k][c]*Wh[r][c] ----------------
// b_comb[r] = sum_c Wh[r][c]*bg[c] + bh[r].  Rows: [ig_mu | ig_std | ia_mu | ia_std]
__global__ void k_comb(const float* __restrict__ Wg, const float* __restrict__ bg,
                       const float* __restrict__ Wig_mu, const float* __restrict__ big_mu,
                       const float* __restrict__ Wig_std, const float* __restrict__ big_std,
                       const float* __restrict__ Wia_mu, const float* __restrict__ bia_mu,
                       const float* __restrict__ Wia_std, const float* __restrict__ bia_std,
                       unsigned short* __restrict__ Wcomb, float* __restrict__ bcomb) {
    const int r = blockIdx.x;      // 0..255
    const int t = threadIdx.x;     // 0..127 (= k)
    const int rr = r & 63;
    const float* Wh; const float* bh;
    switch (r >> 6) {
        case 0:  Wh = Wig_mu;  bh = big_mu;  break;
        case 1:  Wh = Wig_std; bh = big_std; break;
        case 2:  Wh = Wia_mu;  bh = bia_mu;  break;
        default: Wh = Wia_std; bh = bia_std; break;
    }
    __shared__ float sWr[H_DIM];
    sWr[t] = Wh[(size_t)rr * H_DIM + t];
    __syncthreads();
    const float4* wrow = (const float4*)(Wg + (size_t)t * H_DIM);
    float acc = 0.f;
    #pragma unroll 8
    for (int c4 = 0; c4 < 32; ++c4) {
        float4 v = wrow[c4];
        acc = fmaf(v.x, sWr[4 * c4    ], acc);
        acc = fmaf(v.y, sWr[4 * c4 + 1], acc);
        acc = fmaf(v.z, sWr[4 * c4 + 2], acc);
        acc = fmaf(v.w, sWr[4 * c4 + 3], acc);
    }
    Wcomb[r * H_DIM + t] = f2bf(acc);
    if (t == 0) {
        float s = bh[rr];
        for (int c = 0; c < H_DIM; ++c) s = fmaf(bg[c], sWr[c], s);
        bcomb[r] = s;
    }
}

// ---------------- fused: edge aggregation (wave/node) + MFMA combined-head GEMM ----------------
// phase 1: y[n][j] = (g_j*(sum_e p_s*h[s][j] - sum_e q_s) + b_j*sum_e r_s)*nd  -> LDS bf16
// phase 2: out[n][r] = y[n] . W_comb[r] + b_comb[r]  (softplus on std heads)
__launch_bounds__(256)
__global__ void k_fused(const float* __restrict__ h,
                        const int* __restrict__ offs, const int* __restrict__ esrc,
                        const float4* __restrict__ pqr,
                        const float* __restrict__ ln_g, const float* __restrict__ ln_b,
                        const unsigned short* __restrict__ Wcomb,
                        const float* __restrict__ bcomb,
                        float* __restrict__ out) {
    // 16 rows x 136 ushorts (272 B rows: stride 17*16B -> ds_read_b128 only 2-way conflicts)
    __shared__ __align__(16) unsigned short yl[16][136];

    const int tid  = threadIdx.x;
    const int w    = tid >> 6;       // wave 0..3
    const int lane = tid & 63;
    const int l16  = lane & 15;
    const int quad = lane >> 4;
    const long long NI = (long long)N_NODES * I_DIM;

    // persistent B fragments: wave w owns col-tiles 4w..4w+3 (cols (4w+ct)*16+l16)
    bf16x8 B[4][4];
    float bc[4];
    #pragma unroll
    for (int ct = 0; ct < 4; ++ct) {
        int col = (w * 4 + ct) * 16 + l16;
        bc[ct] = bcomb[col];
        #pragma unroll
        for (int kc = 0; kc < 4; ++kc)
            B[ct][kc] = *(const bf16x8*)&Wcomb[col * H_DIM + kc * 32 + quad * 8];
    }
    const float2 g2 = *(const float2*)&ln_g[2 * lane];
    const float2 b2 = *(const float2*)&ln_b[2 * lane];

    for (int tile = blockIdx.x; tile < NT16; tile += gridDim.x) {
        const int base = tile * 16;
        // ---- phase 1: each wave aggregates 4 nodes; lane covers features 2*lane, 2*lane+1 ----
        #pragma unroll
        for (int i = 0; i < 4; ++i) {
            const int nl = w * 4 + i;
            const int n  = base + nl;
            const int s0 = offs[n], s1 = offs[n + 1];
            float ax = 0.f, ay = 0.f, sq = 0.f, sr = 0.f;
            for (int e0 = s0; e0 < s1; e0 += 64) {
                int sv = (e0 + lane < s1) ? esrc[e0 + lane] : 0;
                const int cnt = min(64, s1 - e0);
                for (int k = 0; k < cnt; ++k) {
                    int s = __shfl(sv, k);
                    float4 P = pqr[s];                                   // 16B broadcast
                    float2 hv = *(const float2*)&h[(size_t)s * H_DIM + 2 * lane];
                    ax = fmaf(P.x, hv.x, ax);
                    ay = fmaf(P.x, hv.y, ay);
                    sq += P.y; sr += P.z;
                }
            }
            const int d = s1 - s0;
            const float nd = rsqrtf((float)(d > 0 ? d : 1));
            float y0 = (g2.x * (ax - sq) + b2.x * sr) * nd;
            float y1 = (g2.y * (ay - sq) + b2.y * sr) * nd;
            unsigned int pk = ((unsigned int)f2bf(y1) << 16) | (unsigned int)f2bf(y0);
            *(unsigned int*)&yl[nl][2 * lane] = pk;
        }
        __syncthreads();
        // ---- phase 2: MFMA 16x128 @ 128x256 ----
        bf16x8 A[4];
        #pragma unroll
        for (int kc = 0; kc < 4; ++kc)
            A[kc] = *(const bf16x8*)&yl[l16][kc * 32 + quad * 8];
        #pragma unroll
        for (int ct = 0; ct < 4; ++ct) {
            f32x4 C = {0.f, 0.f, 0.f, 0.f};
            #pragma unroll
            for (int kc = 0; kc < 4; ++kc)
                C = __builtin_amdgcn_mfma_f32_16x16x32_bf16(A[kc], B[ct][kc], C, 0, 0, 0);
            const int col  = (w * 4 + ct) * 16 + l16;
            const int head = col >> 6;
            const int wi   = col & 63;
            const bool sp  = (col & 64) != 0;
            #pragma unroll
            for (int r_ = 0; r_ < 4; ++r_) {
                const int node = base + quad * 4 + r_;
                float v = C[r_] + bc[ct];
                if (sp) v = softplus_f(v);
                out[(long long)head * NI + (long long)node * I_DIM + wi] = v;
            }
        }
        __syncthreads();
    }
}

extern "C" void kernel_launch(void* const* d_in, const int* in_sizes, int n_in,
                              void* d_out, int out_size, void* d_ws, size_t ws_size,
                              hipStream_t stream) {
    const float* actions = (const float*)d_in[0];
    const float* hidden  = (const float*)d_in[1];
    const int*   src     = (const int*)d_in[2];
    const int*   dst     = (const int*)d_in[3];
    const float* W_ih    = (const float*)d_in[4];
    const float* W_hh    = (const float*)d_in[5];
    const float* b_ih    = (const float*)d_in[6];
    const float* b_hh    = (const float*)d_in[7];
    const float* ln_g    = (const float*)d_in[8];
    const float* ln_b    = (const float*)d_in[9];
    const float* Wg      = (const float*)d_in[10];
    const float* bg      = (const float*)d_in[11];
    const float* Wia_mu  = (const float*)d_in[12];
    const float* bia_mu  = (const float*)d_in[13];
    const float* Wia_std = (const float*)d_in[14];
    const float* bia_std = (const float*)d_in[15];
    const float* Wig_mu  = (const float*)d_in[16];
    const float* big_mu  = (const float*)d_in[17];
    const float* Wig_std = (const float*)d_in[18];
    const float* big_std = (const float*)d_in[19];
    float* out = (float*)d_out;

    // ws layout — total ~4.87 MB
    char* w = (char*)d_ws;
    const size_t SZN = 200064;               // N ints, padded to 64
    int*   deg_out = (int*)(w);
    int*   deg_in  = (int*)(w + SZN);
    int*   offs    = (int*)(w + 2 * SZN);    // N+1 ints within padded slot
    int*   cursor  = (int*)(w + 2 * SZN + 200128);
    int*   esrc    = (int*)(w + 3 * SZN + 200128);                       // E ints = 3.2 MB
    float4* pqrA   = (float4*)(w + 3 * SZN + 200128 + 3200000);          // N*16 B = 800 KB (16B aligned)
    unsigned short* Wcomb = (unsigned short*)(w + 3 * SZN + 200128 + 3200000 + 800000);  // 64 KB
    float* bcomb   = (float*)(w + 3 * SZN + 200128 + 3200000 + 800000 + 65536);          // 1 KB
    // end = 600192 + 200128 + 3200000 + 800000 + 65536 + 1024 = 4,866,880 B

    k_zero<<<2048, 256, 0, stream>>>(deg_out, deg_in, cursor, esrc);
    k_hist<<<1024, 256, 0, stream>>>(src, dst, deg_out, deg_in);
    k_scan<<<1, 1024, 0, stream>>>(deg_in, offs);
    k_scatter<<<1024, 256, 0, stream>>>(src, dst, offs, cursor, esrc);
    k_comb<<<256, 128, 0, stream>>>(Wg, bg, Wig_mu, big_mu, Wig_std, big_std,
                                    Wia_mu, bia_mu, Wia_std, bia_std, Wcomb, bcomb);

    // GRU writes f32 h directly into out section 4 (element offset 4*N*I)
    float* h_f = out + (size_t)4 * N_NODES * I_DIM;
    k_gru<<<NT, 512, 0, stream>>>(actions, hidden, W_ih, W_hh, b_ih, b_hh, h_f);

    k_stats<<<(N_NODES + 3) / 4, 256, 0, stream>>>(h_f, deg_out, pqrA);

    k_fused<<<1024, 256, 0, stream>>>(h_f, offs, esrc, pqrA, ln_g, ln_b,
                                      Wcomb, bcomb, out);
}

// Round 3
// 919.061 us; speedup vs baseline: 1.2197x; 1.2197x over previous
//
#include <hip/hip_runtime.h>
#include <hip/hip_bf16.h>
#include <math.h>

constexpr int N_NODES = 50000;
constexpr int T_STEPS = 25;
constexpr int A_DIM   = 16;
constexpr int H_DIM   = 128;
constexpr int G3      = 3 * H_DIM;   // 384
constexpr int E_EDGES = 800000;
constexpr int I_DIM   = 64;
constexpr float LN_EPS = 1e-5f;
constexpr int NT = (N_NODES + 31) / 32;   // 1563 node tiles of 32
constexpr int NT16 = N_NODES / 16;        // 3125 exact (50000 = 16*3125)

using bf16x8 = __attribute__((ext_vector_type(8))) short;
using f32x4  = __attribute__((ext_vector_type(4))) float;

static __device__ __forceinline__ float sigm(float x) { return 1.f / (1.f + __expf(-x)); }
static __device__ __forceinline__ float tanh_fast(float x) { return 2.f / (1.f + __expf(-2.f * x)) - 1.f; }
static __device__ __forceinline__ float softplus_f(float x) {
    return (x > 20.f) ? x : log1pf(__expf(x));
}
static __device__ __forceinline__ unsigned short f2bf(float f) {
    __hip_bfloat16 b = __float2bfloat16(f);   // RNE
    return *(unsigned short*)&b;
}

// ---------------- graph preprocessing ----------------

__global__ void k_zero(int* deg_out, int* deg_in, int* cursor, int* esrc) {
    for (int i = blockIdx.x * blockDim.x + threadIdx.x; i < E_EDGES; i += gridDim.x * blockDim.x) {
        esrc[i] = 0;
        if (i < N_NODES) { deg_out[i] = 0; deg_in[i] = 0; cursor[i] = 0; }
    }
}

__global__ void k_hist(const int* __restrict__ src, const int* __restrict__ dst,
                       int* __restrict__ deg_out, int* __restrict__ deg_in) {
    for (int e = blockIdx.x * blockDim.x + threadIdx.x; e < E_EDGES; e += gridDim.x * blockDim.x) {
        int s = src[e], d = dst[e];
        if (s >= 0 && s < N_NODES) atomicAdd(&deg_out[s], 1);
        if (d >= 0 && d < N_NODES) atomicAdd(&deg_in[d], 1);
    }
}

__launch_bounds__(1024)
__global__ void k_scan(const int* __restrict__ deg, int* __restrict__ offs) {
    __shared__ int wsum[16];
    __shared__ int carry;
    const int tid = threadIdx.x;
    const int lane = tid & 63, wid = tid >> 6;
    if (tid == 0) carry = 0;
    __syncthreads();
    for (int base = 0; base < N_NODES; base += 1024) {
        int i = base + tid;
        int v = (i < N_NODES) ? deg[i] : 0;
        int x = v;
        #pragma unroll
        for (int off = 1; off < 64; off <<= 1) {
            int yv = __shfl_up(x, off);
            if (lane >= off) x += yv;
        }
        if (lane == 63) wsum[wid] = x;
        __syncthreads();
        if (wid == 0 && lane < 16) {
            int s = wsum[lane];
            #pragma unroll
            for (int off = 1; off < 16; off <<= 1) {
                int yv = __shfl_up(s, off, 16);
                if (lane >= off) s += yv;
            }
            wsum[lane] = s;
        }
        __syncthreads();
        int excl = carry + (wid > 0 ? wsum[wid - 1] : 0) + x - v;
        if (i < N_NODES) offs[i] = excl;
        __syncthreads();
        if (tid == 0) carry += wsum[15];
        __syncthreads();
    }
    if (tid == 0) offs[N_NODES] = carry;
}

__global__ void k_scatter(const int* __restrict__ src, const int* __restrict__ dst,
                          const int* __restrict__ offs, int* __restrict__ cursor,
                          int* __restrict__ esrc) {
    for (int e = blockIdx.x * blockDim.x + threadIdx.x; e < E_EDGES; e += gridDim.x * blockDim.x) {
        int d = dst[e];
        if (d < 0 || d >= N_NODES) continue;
        int pos = offs[d] + atomicAdd(&cursor[d], 1);
        if (pos >= 0 && pos < E_EDGES) esrc[pos] = src[e];
    }
}

// ---------------- GRU via MFMA ----------------
// Wave layout restructured: 8 waves = 8 disjoint 16-feature slices (no mt weight
// duplication). Bhh 96->48 VGPRs, Bih 24->12 per lane. launch_bounds(512,4)
// caps combined regs at 128 -> 2 blocks/CU resident (was 1).
__launch_bounds__(512, 4)
__global__ void k_gru(const float* __restrict__ actions,
                      const float* __restrict__ hidden,
                      const float* __restrict__ W_ih,
                      const float* __restrict__ W_hh,
                      const float* __restrict__ b_ih,
                      const float* __restrict__ b_hh,
                      float* __restrict__ h_out) {
    __shared__ __align__(16) unsigned short sX[32 * 424];      // 27.1 KB
    __shared__ __align__(16) unsigned short sH[2][32 * 152];   // 19.5 KB

    const int tid  = threadIdx.x;
    const int w    = tid >> 6;       // 0..7: feature slice
    const int lane = tid & 63;
    const int quad = lane >> 4;
    const int l16  = lane & 15;
    const int j    = 16 * w + l16;   // output feature column, 0..127

    // B fragments: gate gt in {r,z,n}; rows gt*128 + j of W_hh / W_ih
    bf16x8 Bhh[3][4];
    #pragma unroll
    for (int gt = 0; gt < 3; ++gt) {
        const float* rowp = W_hh + (size_t)(gt * H_DIM + j) * H_DIM;
        #pragma unroll
        for (int kc = 0; kc < 4; ++kc) {
            const float* p = rowp + kc * 32 + quad * 8;
            float4 f0 = *(const float4*)p;
            float4 f1 = *(const float4*)(p + 4);
            bf16x8 v;
            v[0] = f2bf(f0.x); v[1] = f2bf(f0.y); v[2] = f2bf(f0.z); v[3] = f2bf(f0.w);
            v[4] = f2bf(f1.x); v[5] = f2bf(f1.y); v[6] = f2bf(f1.z); v[7] = f2bf(f1.w);
            Bhh[gt][kc] = v;
        }
    }
    bf16x8 Bih[3];
    #pragma unroll
    for (int gt = 0; gt < 3; ++gt) {
        bf16x8 v;
        #pragma unroll
        for (int q = 0; q < 8; ++q) v[q] = 0;
        if (quad < 2) {
            const float* p = W_ih + (size_t)(gt * H_DIM + j) * A_DIM + quad * 8;
            float4 f0 = *(const float4*)p;
            float4 f1 = *(const float4*)(p + 4);
            v[0] = f2bf(f0.x); v[1] = f2bf(f0.y); v[2] = f2bf(f0.z); v[3] = f2bf(f0.w);
            v[4] = f2bf(f1.x); v[5] = f2bf(f1.y); v[6] = f2bf(f1.z); v[7] = f2bf(f1.w);
        }
        Bih[gt] = v;
    }
    const float br   = b_ih[j] + b_hh[j];
    const float bz   = b_ih[H_DIM + j] + b_hh[H_DIM + j];
    const float bn_i = b_ih[2 * H_DIM + j];
    const float bn_h = b_hh[2 * H_DIM + j];

    const f32x4 z4 = {0.f, 0.f, 0.f, 0.f};

    for (int tile = blockIdx.x; tile < NT; tile += gridDim.x) {
        const int base = tile * 32;
        for (int idx = tid; idx < 32 * 424; idx += 512) {
            int nl = idx / 424, p = idx - nl * 424;
            int n = base + nl;
            float f = (p < 400 && n < N_NODES) ? actions[(size_t)n * 400 + p] : 0.f;
            sX[nl * 424 + p] = f2bf(f);
        }
        for (int idx = tid; idx < 32 * H_DIM; idx += 512) {
            int nl = idx >> 7, k = idx & 127;
            int n = base + nl;
            sH[0][nl * 152 + k] = f2bf((n < N_NODES) ? hidden[(size_t)n * H_DIM + k] : 0.f);
        }
        float hp[2][4];
        #pragma unroll
        for (int m = 0; m < 2; ++m)
            #pragma unroll
            for (int r = 0; r < 4; ++r) {
                int n = base + m * 16 + quad * 4 + r;
                hp[m][r] = (n < N_NODES) ? hidden[(size_t)n * H_DIM + j] : 0.f;
            }
        __syncthreads();

        int cur = 0;
        for (int t = 0; t < T_STEPS; ++t) {
            const int nxt = cur ^ 1;
            #pragma unroll
            for (int m = 0; m < 2; ++m) {
                bf16x8 ax = *(const bf16x8*)&sX[(m * 16 + l16) * 424 + t * 16 + quad * 8];
                if (quad >= 2) {
                    #pragma unroll
                    for (int q = 0; q < 8; ++q) ax[q] = 0;
                }
                f32x4 Cr = __builtin_amdgcn_mfma_f32_16x16x32_bf16(ax, Bih[0], z4, 0, 0, 0);
                f32x4 Cz = __builtin_amdgcn_mfma_f32_16x16x32_bf16(ax, Bih[1], z4, 0, 0, 0);
                f32x4 Cn = __builtin_amdgcn_mfma_f32_16x16x32_bf16(ax, Bih[2], z4, 0, 0, 0);
                f32x4 Ch = z4;
                #pragma unroll
                for (int kc = 0; kc < 4; ++kc) {
                    bf16x8 ah = *(const bf16x8*)&sH[cur][(m * 16 + l16) * 152 + kc * 32 + quad * 8];
                    Cr = __builtin_amdgcn_mfma_f32_16x16x32_bf16(ah, Bhh[0][kc], Cr, 0, 0, 0);
                    Cz = __builtin_amdgcn_mfma_f32_16x16x32_bf16(ah, Bhh[1][kc], Cz, 0, 0, 0);
                    Ch = __builtin_amdgcn_mfma_f32_16x16x32_bf16(ah, Bhh[2][kc], Ch, 0, 0, 0);
                }
                #pragma unroll
                for (int r = 0; r < 4; ++r) {
                    float rg = sigm(Cr[r] + br);
                    float zg = sigm(Cz[r] + bz);
                    float ng = tanh_fast(Cn[r] + bn_i + rg * (Ch[r] + bn_h));
                    float h2 = ng + zg * (hp[m][r] - ng);
                    hp[m][r] = h2;
                    sH[nxt][(m * 16 + quad * 4 + r) * 152 + j] = f2bf(h2);
                }
            }
            cur = nxt;
            __syncthreads();
        }
        #pragma unroll
        for (int m = 0; m < 2; ++m)
            #pragma unroll
            for (int r = 0; r < 4; ++r) {
                int n = base + m * 16 + quad * 4 + r;
                if (n < N_NODES) h_out[(size_t)n * H_DIM + j] = hp[m][r];
            }
        __syncthreads();
    }
}

// ---------------- per-node LN stats packed: pqr[n] = {inv*ns, mu*inv*ns, ns, 0} ----------------
__global__ void k_stats(const float* __restrict__ h, const int* __restrict__ deg_out,
                        float4* __restrict__ pqr) {
    int n = blockIdx.x * (blockDim.x >> 6) + (threadIdx.x >> 6);
    int lane = threadIdx.x & 63;
    if (n >= N_NODES) return;
    float v0 = h[(size_t)n * H_DIM + lane];
    float v1 = h[(size_t)n * H_DIM + 64 + lane];
    float s = v0 + v1, qq = v0 * v0 + v1 * v1;
    #pragma unroll
    for (int m = 32; m; m >>= 1) { s += __shfl_xor(s, m); qq += __shfl_xor(qq, m); }
    float mu = s * (1.f / H_DIM);
    float var = fmaxf(qq * (1.f / H_DIM) - mu * mu, 0.f);
    float inv = rsqrtf(var + LN_EPS);
    int d = deg_out[n];
    float ns = rsqrtf((float)(d > 0 ? d : 1));
    if (lane == 0) pqr[n] = make_float4(inv * ns, mu * inv * ns, ns, 0.f);
}

// ---------------- fold Wg into the 4 heads: W_comb[r][k] = sum_c Wg[k][c]*Wh[r][c] ----------------
// b_comb[r] = sum_c Wh[r][c]*bg[c] + bh[r].  Rows: [ig_mu | ig_std | ia_mu | ia_std]
__global__ void k_comb(const float* __restrict__ Wg, const float* __restrict__ bg,
                       const float* __restrict__ Wig_mu, const float* __restrict__ big_mu,
                       const float* __restrict__ Wig_std, const float* __restrict__ big_std,
                       const float* __restrict__ Wia_mu, const float* __restrict__ bia_mu,
                       const float* __restrict__ Wia_std, const float* __restrict__ bia_std,
                       unsigned short* __restrict__ Wcomb, float* __restrict__ bcomb) {
    const int r = blockIdx.x;      // 0..255
    const int t = threadIdx.x;     // 0..127 (= k)
    const int rr = r & 63;
    const float* Wh; const float* bh;
    switch (r >> 6) {
        case 0:  Wh = Wig_mu;  bh = big_mu;  break;
        case 1:  Wh = Wig_std; bh = big_std; break;
        case 2:  Wh = Wia_mu;  bh = bia_mu;  break;
        default: Wh = Wia_std; bh = bia_std; break;
    }
    __shared__ float sWr[H_DIM];
    sWr[t] = Wh[(size_t)rr * H_DIM + t];
    __syncthreads();
    const float4* wrow = (const float4*)(Wg + (size_t)t * H_DIM);
    float acc = 0.f;
    #pragma unroll 8
    for (int c4 = 0; c4 < 32; ++c4) {
        float4 v = wrow[c4];
        acc = fmaf(v.x, sWr[4 * c4    ], acc);
        acc = fmaf(v.y, sWr[4 * c4 + 1], acc);
        acc = fmaf(v.z, sWr[4 * c4 + 2], acc);
        acc = fmaf(v.w, sWr[4 * c4 + 3], acc);
    }
    Wcomb[r * H_DIM + t] = f2bf(acc);
    if (t == 0) {
        float s = bh[rr];
        for (int c = 0; c < H_DIM; ++c) s = fmaf(bg[c], sWr[c], s);
        bcomb[r] = s;
    }
}

// ---------------- fused: edge aggregation (wave/node) + MFMA combined-head GEMM ----------------
// phase 1: y[n][j] = (g_j*(sum_e p_s*h[s][j] - sum_e q_s) + b_j*sum_e r_s)*nd  -> LDS bf16
// phase 2: out[n][r] = y[n] . W_comb[r] + b_comb[r]  (softplus on std heads)
__launch_bounds__(256)
__global__ void k_fused(const float* __restrict__ h,
                        const int* __restrict__ offs, const int* __restrict__ esrc,
                        const float4* __restrict__ pqr,
                        const float* __restrict__ ln_g, const float* __restrict__ ln_b,
                        const unsigned short* __restrict__ Wcomb,
                        const float* __restrict__ bcomb,
                        float* __restrict__ out) {
    // 16 rows x 136 ushorts (272 B rows: stride 17*16B -> ds_read_b128 only 2-way conflicts)
    __shared__ __align__(16) unsigned short yl[16][136];

    const int tid  = threadIdx.x;
    const int w    = tid >> 6;       // wave 0..3
    const int lane = tid & 63;
    const int l16  = lane & 15;
    const int quad = lane >> 4;
    const long long NI = (long long)N_NODES * I_DIM;

    // persistent B fragments: wave w owns col-tiles 4w..4w+3 (cols (4w+ct)*16+l16)
    bf16x8 B[4][4];
    float bc[4];
    #pragma unroll
    for (int ct = 0; ct < 4; ++ct) {
        int col = (w * 4 + ct) * 16 + l16;
        bc[ct] = bcomb[col];
        #pragma unroll
        for (int kc = 0; kc < 4; ++kc)
            B[ct][kc] = *(const bf16x8*)&Wcomb[col * H_DIM + kc * 32 + quad * 8];
    }
    const float2 g2 = *(const float2*)&ln_g[2 * lane];
    const float2 b2 = *(const float2*)&ln_b[2 * lane];

    for (int tile = blockIdx.x; tile < NT16; tile += gridDim.x) {
        const int base = tile * 16;
        // ---- phase 1: each wave aggregates 4 nodes; lane covers features 2*lane, 2*lane+1 ----
        #pragma unroll
        for (int i = 0; i < 4; ++i) {
            const int nl = w * 4 + i;
            const int n  = base + nl;
            const int s0 = offs[n], s1 = offs[n + 1];
            float ax = 0.f, ay = 0.f, sq = 0.f, sr = 0.f;
            for (int e0 = s0; e0 < s1; e0 += 64) {
                int sv = (e0 + lane < s1) ? esrc[e0 + lane] : 0;
                const int cnt = min(64, s1 - e0);
                for (int k = 0; k < cnt; ++k) {
                    int s = __shfl(sv, k);
                    float4 P = pqr[s];                                   // 16B broadcast
                    float2 hv = *(const float2*)&h[(size_t)s * H_DIM + 2 * lane];
                    ax = fmaf(P.x, hv.x, ax);
                    ay = fmaf(P.x, hv.y, ay);
                    sq += P.y; sr += P.z;
                }
            }
            const int d = s1 - s0;
            const float nd = rsqrtf((float)(d > 0 ? d : 1));
            float y0 = (g2.x * (ax - sq) + b2.x * sr) * nd;
            float y1 = (g2.y * (ay - sq) + b2.y * sr) * nd;
            unsigned int pk = ((unsigned int)f2bf(y1) << 16) | (unsigned int)f2bf(y0);
            *(unsigned int*)&yl[nl][2 * lane] = pk;
        }
        __syncthreads();
        // ---- phase 2: MFMA 16x128 @ 128x256 ----
        bf16x8 A[4];
        #pragma unroll
        for (int kc = 0; kc < 4; ++kc)
            A[kc] = *(const bf16x8*)&yl[l16][kc * 32 + quad * 8];
        #pragma unroll
        for (int ct = 0; ct < 4; ++ct) {
            f32x4 C = {0.f, 0.f, 0.f, 0.f};
            #pragma unroll
            for (int kc = 0; kc < 4; ++kc)
                C = __builtin_amdgcn_mfma_f32_16x16x32_bf16(A[kc], B[ct][kc], C, 0, 0, 0);
            const int col  = (w * 4 + ct) * 16 + l16;
            const int head = col >> 6;
            const int wi   = col & 63;
            const bool sp  = (col & 64) != 0;
            #pragma unroll
            for (int r_ = 0; r_ < 4; ++r_) {
                const int node = base + quad * 4 + r_;
                float v = C[r_] + bc[ct];
                if (sp) v = softplus_f(v);
                out[(long long)head * NI + (long long)node * I_DIM + wi] = v;
            }
        }
        __syncthreads();
    }
}

extern "C" void kernel_launch(void* const* d_in, const int* in_sizes, int n_in,
                              void* d_out, int out_size, void* d_ws, size_t ws_size,
                              hipStream_t stream) {
    const float* actions = (const float*)d_in[0];
    const float* hidden  = (const float*)d_in[1];
    const int*   src     = (const int*)d_in[2];
    const int*   dst     = (const int*)d_in[3];
    const float* W_ih    = (const float*)d_in[4];
    const float* W_hh    = (const float*)d_in[5];
    const float* b_ih    = (const float*)d_in[6];
    const float* b_hh    = (const float*)d_in[7];
    const float* ln_g    = (const float*)d_in[8];
    const float* ln_b    = (const float*)d_in[9];
    const float* Wg      = (const float*)d_in[10];
    const float* bg      = (const float*)d_in[11];
    const float* Wia_mu  = (const float*)d_in[12];
    const float* bia_mu  = (const float*)d_in[13];
    const float* Wia_std = (const float*)d_in[14];
    const float* bia_std = (const float*)d_in[15];
    const float* Wig_mu  = (const float*)d_in[16];
    const float* big_mu  = (const float*)d_in[17];
    const float* Wig_std = (const float*)d_in[18];
    const float* big_std = (const float*)d_in[19];
    float* out = (float*)d_out;

    // ws layout — total ~4.87 MB
    char* w = (char*)d_ws;
    const size_t SZN = 200064;               // N ints, padded to 64
    int*   deg_out = (int*)(w);
    int*   deg_in  = (int*)(w + SZN);
    int*   offs    = (int*)(w + 2 * SZN);    // N+1 ints within padded slot
    int*   cursor  = (int*)(w + 2 * SZN + 200128);
    int*   esrc    = (int*)(w + 3 * SZN + 200128);                       // E ints = 3.2 MB
    float4* pqrA   = (float4*)(w + 3 * SZN + 200128 + 3200000);          // N*16 B = 800 KB (16B aligned)
    unsigned short* Wcomb = (unsigned short*)(w + 3 * SZN + 200128 + 3200000 + 800000);  // 64 KB
    float* bcomb   = (float*)(w + 3 * SZN + 200128 + 3200000 + 800000 + 65536);          // 1 KB
    // end = 600192 + 200128 + 3200000 + 800000 + 65536 + 1024 = 4,866,880 B

    k_zero<<<2048, 256, 0, stream>>>(deg_out, deg_in, cursor, esrc);
    k_hist<<<1024, 256, 0, stream>>>(src, dst, deg_out, deg_in);
    k_scan<<<1, 1024, 0, stream>>>(deg_in, offs);
    k_scatter<<<1024, 256, 0, stream>>>(src, dst, offs, cursor, esrc);
    k_comb<<<256, 128, 0, stream>>>(Wg, bg, Wig_mu, big_mu, Wig_std, big_std,
                                    Wia_mu, bia_mu, Wia_std, bia_std, Wcomb, bcomb);

    // GRU writes f32 h directly into out section 4 (element offset 4*N*I)
    float* h_f = out + (size_t)4 * N_NODES * I_DIM;
    k_gru<<<512, 512, 0, stream>>>(actions, hidden, W_ih, W_hh, b_ih, b_hh, h_f);

    k_stats<<<(N_NODES + 3) / 4, 256, 0, stream>>>(h_f, deg_out, pqrA);

    k_fused<<<1024, 256, 0, stream>>>(h_f, offs, esrc, pqrA, ln_g, ln_b,
                                      Wcomb, bcomb, out);
}

// Round 4
// 902.462 us; speedup vs baseline: 1.2421x; 1.0184x over previous
//
#include <hip/hip_runtime.h>
#include <hip/hip_bf16.h>
#include <math.h>

constexpr int N_NODES = 50000;
constexpr int T_STEPS = 25;
constexpr int A_DIM   = 16;
constexpr int H_DIM   = 128;
constexpr int G3      = 3 * H_DIM;   // 384
constexpr int E_EDGES = 800000;
constexpr int I_DIM   = 64;
constexpr float LN_EPS = 1e-5f;
constexpr int NT = (N_NODES + 31) / 32;   // 1563 node tiles of 32
constexpr int NT16 = N_NODES / 16;        // 3125 exact (50000 = 16*3125)

using bf16x8 = __attribute__((ext_vector_type(8))) short;
using f32x4  = __attribute__((ext_vector_type(4))) float;

static __device__ __forceinline__ float sigm(float x) { return 1.f / (1.f + __expf(-x)); }
static __device__ __forceinline__ float tanh_fast(float x) { return 2.f / (1.f + __expf(-2.f * x)) - 1.f; }
static __device__ __forceinline__ float softplus_f(float x) {
    return (x > 20.f) ? x : log1pf(__expf(x));
}
static __device__ __forceinline__ unsigned short f2bf(float f) {
    __hip_bfloat16 b = __float2bfloat16(f);   // RNE
    return *(unsigned short*)&b;
}

// ---------------- graph preprocessing ----------------

__global__ void k_zero(int* deg_out, int* deg_in, int* cursor, int* esrc) {
    for (int i = blockIdx.x * blockDim.x + threadIdx.x; i < E_EDGES; i += gridDim.x * blockDim.x) {
        esrc[i] = 0;
        if (i < N_NODES) { deg_out[i] = 0; deg_in[i] = 0; cursor[i] = 0; }
    }
}

__global__ void k_hist(const int* __restrict__ src, const int* __restrict__ dst,
                       int* __restrict__ deg_out, int* __restrict__ deg_in) {
    for (int e = blockIdx.x * blockDim.x + threadIdx.x; e < E_EDGES; e += gridDim.x * blockDim.x) {
        int s = src[e], d = dst[e];
        if (s >= 0 && s < N_NODES) atomicAdd(&deg_out[s], 1);
        if (d >= 0 && d < N_NODES) atomicAdd(&deg_in[d], 1);
    }
}

__launch_bounds__(1024)
__global__ void k_scan(const int* __restrict__ deg, int* __restrict__ offs) {
    __shared__ int wsum[16];
    __shared__ int carry;
    const int tid = threadIdx.x;
    const int lane = tid & 63, wid = tid >> 6;
    if (tid == 0) carry = 0;
    __syncthreads();
    for (int base = 0; base < N_NODES; base += 1024) {
        int i = base + tid;
        int v = (i < N_NODES) ? deg[i] : 0;
        int x = v;
        #pragma unroll
        for (int off = 1; off < 64; off <<= 1) {
            int yv = __shfl_up(x, off);
            if (lane >= off) x += yv;
        }
        if (lane == 63) wsum[wid] = x;
        __syncthreads();
        if (wid == 0 && lane < 16) {
            int s = wsum[lane];
            #pragma unroll
            for (int off = 1; off < 16; off <<= 1) {
                int yv = __shfl_up(s, off, 16);
                if (lane >= off) s += yv;
            }
            wsum[lane] = s;
        }
        __syncthreads();
        int excl = carry + (wid > 0 ? wsum[wid - 1] : 0) + x - v;
        if (i < N_NODES) offs[i] = excl;
        __syncthreads();
        if (tid == 0) carry += wsum[15];
        __syncthreads();
    }
    if (tid == 0) offs[N_NODES] = carry;
}

__global__ void k_scatter(const int* __restrict__ src, const int* __restrict__ dst,
                          const int* __restrict__ offs, int* __restrict__ cursor,
                          int* __restrict__ esrc) {
    for (int e = blockIdx.x * blockDim.x + threadIdx.x; e < E_EDGES; e += gridDim.x * blockDim.x) {
        int d = dst[e];
        if (d < 0 || d >= N_NODES) continue;
        int pos = offs[d] + atomicAdd(&cursor[d], 1);
        if (pos >= 0 && pos < E_EDGES) esrc[pos] = src[e];
    }
}

// ---------------- GRU via MFMA ----------------
// 8 waves = 8 disjoint 16-feature slices. VGPR=64, LDS 46.6KB -> 3 blocks/CU.
// grid 768 = exactly 3 blocks/CU (round 3: grid 512 left a residency slot empty).
__launch_bounds__(512, 4)
__global__ void k_gru(const float* __restrict__ actions,
                      const float* __restrict__ hidden,
                      const float* __restrict__ W_ih,
                      const float* __restrict__ W_hh,
                      const float* __restrict__ b_ih,
                      const float* __restrict__ b_hh,
                      float* __restrict__ h_out) {
    __shared__ __align__(16) unsigned short sX[32 * 424];      // 27.1 KB
    __shared__ __align__(16) unsigned short sH[2][32 * 152];   // 19.5 KB

    const int tid  = threadIdx.x;
    const int w    = tid >> 6;       // 0..7: feature slice
    const int lane = tid & 63;
    const int quad = lane >> 4;
    const int l16  = lane & 15;
    const int j    = 16 * w + l16;   // output feature column, 0..127

    // B fragments: gate gt in {r,z,n}; rows gt*128 + j of W_hh / W_ih
    bf16x8 Bhh[3][4];
    #pragma unroll
    for (int gt = 0; gt < 3; ++gt) {
        const float* rowp = W_hh + (size_t)(gt * H_DIM + j) * H_DIM;
        #pragma unroll
        for (int kc = 0; kc < 4; ++kc) {
            const float* p = rowp + kc * 32 + quad * 8;
            float4 f0 = *(const float4*)p;
            float4 f1 = *(const float4*)(p + 4);
            bf16x8 v;
            v[0] = f2bf(f0.x); v[1] = f2bf(f0.y); v[2] = f2bf(f0.z); v[3] = f2bf(f0.w);
            v[4] = f2bf(f1.x); v[5] = f2bf(f1.y); v[6] = f2bf(f1.z); v[7] = f2bf(f1.w);
            Bhh[gt][kc] = v;
        }
    }
    bf16x8 Bih[3];
    #pragma unroll
    for (int gt = 0; gt < 3; ++gt) {
        bf16x8 v;
        #pragma unroll
        for (int q = 0; q < 8; ++q) v[q] = 0;
        if (quad < 2) {
            const float* p = W_ih + (size_t)(gt * H_DIM + j) * A_DIM + quad * 8;
            float4 f0 = *(const float4*)p;
            float4 f1 = *(const float4*)(p + 4);
            v[0] = f2bf(f0.x); v[1] = f2bf(f0.y); v[2] = f2bf(f0.z); v[3] = f2bf(f0.w);
            v[4] = f2bf(f1.x); v[5] = f2bf(f1.y); v[6] = f2bf(f1.z); v[7] = f2bf(f1.w);
        }
        Bih[gt] = v;
    }
    const float br   = b_ih[j] + b_hh[j];
    const float bz   = b_ih[H_DIM + j] + b_hh[H_DIM + j];
    const float bn_i = b_ih[2 * H_DIM + j];
    const float bn_h = b_hh[2 * H_DIM + j];

    const f32x4 z4 = {0.f, 0.f, 0.f, 0.f};

    for (int tile = blockIdx.x; tile < NT; tile += gridDim.x) {
        const int base = tile * 32;
        for (int idx = tid; idx < 32 * 424; idx += 512) {
            int nl = idx / 424, p = idx - nl * 424;
            int n = base + nl;
            float f = (p < 400 && n < N_NODES) ? actions[(size_t)n * 400 + p] : 0.f;
            sX[nl * 424 + p] = f2bf(f);
        }
        for (int idx = tid; idx < 32 * H_DIM; idx += 512) {
            int nl = idx >> 7, k = idx & 127;
            int n = base + nl;
            sH[0][nl * 152 + k] = f2bf((n < N_NODES) ? hidden[(size_t)n * H_DIM + k] : 0.f);
        }
        float hp[2][4];
        #pragma unroll
        for (int m = 0; m < 2; ++m)
            #pragma unroll
            for (int r = 0; r < 4; ++r) {
                int n = base + m * 16 + quad * 4 + r;
                hp[m][r] = (n < N_NODES) ? hidden[(size_t)n * H_DIM + j] : 0.f;
            }
        __syncthreads();

        int cur = 0;
        for (int t = 0; t < T_STEPS; ++t) {
            const int nxt = cur ^ 1;
            #pragma unroll
            for (int m = 0; m < 2; ++m) {
                bf16x8 ax = *(const bf16x8*)&sX[(m * 16 + l16) * 424 + t * 16 + quad * 8];
                if (quad >= 2) {
                    #pragma unroll
                    for (int q = 0; q < 8; ++q) ax[q] = 0;
                }
                f32x4 Cr = __builtin_amdgcn_mfma_f32_16x16x32_bf16(ax, Bih[0], z4, 0, 0, 0);
                f32x4 Cz = __builtin_amdgcn_mfma_f32_16x16x32_bf16(ax, Bih[1], z4, 0, 0, 0);
                f32x4 Cn = __builtin_amdgcn_mfma_f32_16x16x32_bf16(ax, Bih[2], z4, 0, 0, 0);
                f32x4 Ch = z4;
                #pragma unroll
                for (int kc = 0; kc < 4; ++kc) {
                    bf16x8 ah = *(const bf16x8*)&sH[cur][(m * 16 + l16) * 152 + kc * 32 + quad * 8];
                    Cr = __builtin_amdgcn_mfma_f32_16x16x32_bf16(ah, Bhh[0][kc], Cr, 0, 0, 0);
                    Cz = __builtin_amdgcn_mfma_f32_16x16x32_bf16(ah, Bhh[1][kc], Cz, 0, 0, 0);
                    Ch = __builtin_amdgcn_mfma_f32_16x16x32_bf16(ah, Bhh[2][kc], Ch, 0, 0, 0);
                }
                #pragma unroll
                for (int r = 0; r < 4; ++r) {
                    float rg = sigm(Cr[r] + br);
                    float zg = sigm(Cz[r] + bz);
                    float ng = tanh_fast(Cn[r] + bn_i + rg * (Ch[r] + bn_h));
                    float h2 = ng + zg * (hp[m][r] - ng);
                    hp[m][r] = h2;
                    sH[nxt][(m * 16 + quad * 4 + r) * 152 + j] = f2bf(h2);
                }
            }
            cur = nxt;
            __syncthreads();
        }
        #pragma unroll
        for (int m = 0; m < 2; ++m)
            #pragma unroll
            for (int r = 0; r < 4; ++r) {
                int n = base + m * 16 + quad * 4 + r;
                if (n < N_NODES) h_out[(size_t)n * H_DIM + j] = hp[m][r];
            }
        __syncthreads();
    }
}

// ---------------- per-node LN stats packed: pqr[n] = {inv*ns, mu*inv*ns, ns, 0} ----------------
__global__ void k_stats(const float* __restrict__ h, const int* __restrict__ deg_out,
                        float4* __restrict__ pqr) {
    int n = blockIdx.x * (blockDim.x >> 6) + (threadIdx.x >> 6);
    int lane = threadIdx.x & 63;
    if (n >= N_NODES) return;
    float v0 = h[(size_t)n * H_DIM + lane];
    float v1 = h[(size_t)n * H_DIM + 64 + lane];
    float s = v0 + v1, qq = v0 * v0 + v1 * v1;
    #pragma unroll
    for (int m = 32; m; m >>= 1) { s += __shfl_xor(s, m); qq += __shfl_xor(qq, m); }
    float mu = s * (1.f / H_DIM);
    float var = fmaxf(qq * (1.f / H_DIM) - mu * mu, 0.f);
    float inv = rsqrtf(var + LN_EPS);
    int d = deg_out[n];
    float ns = rsqrtf((float)(d > 0 ? d : 1));
    if (lane == 0) pqr[n] = make_float4(inv * ns, mu * inv * ns, ns, 0.f);
}

// ---------------- fold Wg into the 4 heads: W_comb[r][k] = sum_c Wg[k][c]*Wh[r][c] ----------------
// b_comb[r] = sum_c Wh[r][c]*bg[c] + bh[r].  Rows: [ig_mu | ig_std | ia_mu | ia_std]
__global__ void k_comb(const float* __restrict__ Wg, const float* __restrict__ bg,
                       const float* __restrict__ Wig_mu, const float* __restrict__ big_mu,
                       const float* __restrict__ Wig_std, const float* __restrict__ big_std,
                       const float* __restrict__ Wia_mu, const float* __restrict__ bia_mu,
                       const float* __restrict__ Wia_std, const float* __restrict__ bia_std,
                       unsigned short* __restrict__ Wcomb, float* __restrict__ bcomb) {
    const int r = blockIdx.x;      // 0..255
    const int t = threadIdx.x;     // 0..127 (= k)
    const int rr = r & 63;
    const float* Wh; const float* bh;
    switch (r >> 6) {
        case 0:  Wh = Wig_mu;  bh = big_mu;  break;
        case 1:  Wh = Wig_std; bh = big_std; break;
        case 2:  Wh = Wia_mu;  bh = bia_mu;  break;
        default: Wh = Wia_std; bh = bia_std; break;
    }
    __shared__ float sWr[H_DIM];
    sWr[t] = Wh[(size_t)rr * H_DIM + t];
    __syncthreads();
    const float4* wrow = (const float4*)(Wg + (size_t)t * H_DIM);
    float acc = 0.f;
    #pragma unroll 8
    for (int c4 = 0; c4 < 32; ++c4) {
        float4 v = wrow[c4];
        acc = fmaf(v.x, sWr[4 * c4    ], acc);
        acc = fmaf(v.y, sWr[4 * c4 + 1], acc);
        acc = fmaf(v.z, sWr[4 * c4 + 2], acc);
        acc = fmaf(v.w, sWr[4 * c4 + 3], acc);
    }
    Wcomb[r * H_DIM + t] = f2bf(acc);
    if (t == 0) {
        float s = bh[rr];
        for (int c = 0; c < H_DIM; ++c) s = fmaf(bg[c], sWr[c], s);
        bcomb[r] = s;
    }
}

// ---------------- fused: edge aggregation (wave/node) + MFMA combined-head GEMM ----------------
// phase 1: y[n][j] = (g_j*(sum_e p_s*h[s][j] - sum_e q_s) + b_j*sum_e r_s)*nd  -> LDS bf16
// phase 2: out[n][r] = y[n] . W_comb[r] + b_comb[r]  (softplus on std heads)
__launch_bounds__(256)
__global__ void k_fused(const float* __restrict__ h,
                        const int* __restrict__ offs, const int* __restrict__ esrc,
                        const float4* __restrict__ pqr,
                        const float* __restrict__ ln_g, const float* __restrict__ ln_b,
                        const unsigned short* __restrict__ Wcomb,
                        const float* __restrict__ bcomb,
                        float* __restrict__ out) {
    // 16 rows x 136 ushorts (272 B rows: stride 17*16B -> ds_read_b128 only 2-way conflicts)
    __shared__ __align__(16) unsigned short yl[16][136];

    const int tid  = threadIdx.x;
    const int w    = tid >> 6;       // wave 0..3
    const int lane = tid & 63;
    const int l16  = lane & 15;
    const int quad = lane >> 4;
    const long long NI = (long long)N_NODES * I_DIM;

    // persistent B fragments: wave w owns col-tiles 4w..4w+3 (cols (4w+ct)*16+l16)
    bf16x8 B[4][4];
    float bc[4];
    #pragma unroll
    for (int ct = 0; ct < 4; ++ct) {
        int col = (w * 4 + ct) * 16 + l16;
        bc[ct] = bcomb[col];
        #pragma unroll
        for (int kc = 0; kc < 4; ++kc)
            B[ct][kc] = *(const bf16x8*)&Wcomb[col * H_DIM + kc * 32 + quad * 8];
    }
    const float2 g2 = *(const float2*)&ln_g[2 * lane];
    const float2 b2 = *(const float2*)&ln_b[2 * lane];

    for (int tile = blockIdx.x; tile < NT16; tile += gridDim.x) {
        const int base = tile * 16;
        // ---- phase 1: each wave aggregates 4 nodes; lane covers features 2*lane, 2*lane+1 ----
        #pragma unroll
        for (int i = 0; i < 4; ++i) {
            const int nl = w * 4 + i;
            const int n  = base + nl;
            const int s0 = offs[n], s1 = offs[n + 1];
            float ax = 0.f, ay = 0.f, sq = 0.f, sr = 0.f;
            for (int e0 = s0; e0 < s1; e0 += 64) {
                int sv = (e0 + lane < s1) ? esrc[e0 + lane] : 0;
                const int cnt = min(64, s1 - e0);
                for (int k = 0; k < cnt; ++k) {
                    int s = __shfl(sv, k);
                    float4 P = pqr[s];                                   // 16B broadcast
                    float2 hv = *(const float2*)&h[(size_t)s * H_DIM + 2 * lane];
                    ax = fmaf(P.x, hv.x, ax);
                    ay = fmaf(P.x, hv.y, ay);
                    sq += P.y; sr += P.z;
                }
            }
            const int d = s1 - s0;
            const float nd = rsqrtf((float)(d > 0 ? d : 1));
            float y0 = (g2.x * (ax - sq) + b2.x * sr) * nd;
            float y1 = (g2.y * (ay - sq) + b2.y * sr) * nd;
            unsigned int pk = ((unsigned int)f2bf(y1) << 16) | (unsigned int)f2bf(y0);
            *(unsigned int*)&yl[nl][2 * lane] = pk;
        }
        __syncthreads();
        // ---- phase 2: MFMA 16x128 @ 128x256 ----
        bf16x8 A[4];
        #pragma unroll
        for (int kc = 0; kc < 4; ++kc)
            A[kc] = *(const bf16x8*)&yl[l16][kc * 32 + quad * 8];
        #pragma unroll
        for (int ct = 0; ct < 4; ++ct) {
            f32x4 C = {0.f, 0.f, 0.f, 0.f};
            #pragma unroll
            for (int kc = 0; kc < 4; ++kc)
                C = __builtin_amdgcn_mfma_f32_16x16x32_bf16(A[kc], B[ct][kc], C, 0, 0, 0);
            const int col  = (w * 4 + ct) * 16 + l16;
            const int head = col >> 6;
            const int wi   = col & 63;
            const bool sp  = (col & 64) != 0;
            #pragma unroll
            for (int r_ = 0; r_ < 4; ++r_) {
                const int node = base + quad * 4 + r_;
                float v = C[r_] + bc[ct];
                if (sp) v = softplus_f(v);
                out[(long long)head * NI + (long long)node * I_DIM + wi] = v;
            }
        }
        __syncthreads();
    }
}

extern "C" void kernel_launch(void* const* d_in, const int* in_sizes, int n_in,
                              void* d_out, int out_size, void* d_ws, size_t ws_size,
                              hipStream_t stream) {
    const float* actions = (const float*)d_in[0];
    const float* hidden  = (const float*)d_in[1];
    const int*   src     = (const int*)d_in[2];
    const int*   dst     = (const int*)d_in[3];
    const float* W_ih    = (const float*)d_in[4];
    const float* W_hh    = (const float*)d_in[5];
    const float* b_ih    = (const float*)d_in[6];
    const float* b_hh    = (const float*)d_in[7];
    const float* ln_g    = (const float*)d_in[8];
    const float* ln_b    = (const float*)d_in[9];
    const float* Wg      = (const float*)d_in[10];
    const float* bg      = (const float*)d_in[11];
    const float* Wia_mu  = (const float*)d_in[12];
    const float* bia_mu  = (const float*)d_in[13];
    const float* Wia_std = (const float*)d_in[14];
    const float* bia_std = (const float*)d_in[15];
    const float* Wig_mu  = (const float*)d_in[16];
    const float* big_mu  = (const float*)d_in[17];
    const float* Wig_std = (const float*)d_in[18];
    const float* big_std = (const float*)d_in[19];
    float* out = (float*)d_out;

    // ws layout — total ~4.87 MB
    char* w = (char*)d_ws;
    const size_t SZN = 200064;               // N ints, padded to 64
    int*   deg_out = (int*)(w);
    int*   deg_in  = (int*)(w + SZN);
    int*   offs    = (int*)(w + 2 * SZN);    // N+1 ints within padded slot
    int*   cursor  = (int*)(w + 2 * SZN + 200128);
    int*   esrc    = (int*)(w + 3 * SZN + 200128);                       // E ints = 3.2 MB
    float4* pqrA   = (float4*)(w + 3 * SZN + 200128 + 3200000);          // N*16 B = 800 KB (16B aligned)
    unsigned short* Wcomb = (unsigned short*)(w + 3 * SZN + 200128 + 3200000 + 800000);  // 64 KB
    float* bcomb   = (float*)(w + 3 * SZN + 200128 + 3200000 + 800000 + 65536);          // 1 KB
    // end = 600192 + 200128 + 3200000 + 800000 + 65536 + 1024 = 4,866,880 B

    k_zero<<<2048, 256, 0, stream>>>(deg_out, deg_in, cursor, esrc);
    k_hist<<<1024, 256, 0, stream>>>(src, dst, deg_out, deg_in);
    k_scan<<<1, 1024, 0, stream>>>(deg_in, offs);
    k_scatter<<<1024, 256, 0, stream>>>(src, dst, offs, cursor, esrc);
    k_comb<<<256, 128, 0, stream>>>(Wg, bg, Wig_mu, big_mu, Wig_std, big_std,
                                    Wia_mu, bia_mu, Wia_std, bia_std, Wcomb, bcomb);

    // GRU writes f32 h directly into out section 4 (element offset 4*N*I)
    float* h_f = out + (size_t)4 * N_NODES * I_DIM;
    k_gru<<<768, 512, 0, stream>>>(actions, hidden, W_ih, W_hh, b_ih, b_hh, h_f);

    k_stats<<<(N_NODES + 3) / 4, 256, 0, stream>>>(h_f, deg_out, pqrA);

    k_fused<<<2048, 256, 0, stream>>>(h_f, offs, esrc, pqrA, ln_g, ln_b,
                                      Wcomb, bcomb, out);
}

// Round 5
// 890.066 us; speedup vs baseline: 1.2594x; 1.0139x over previous
//
#include <hip/hip_runtime.h>
#include <hip/hip_bf16.h>
#include <math.h>

constexpr int N_NODES = 50000;
constexpr int T_STEPS = 25;
constexpr int A_DIM   = 16;
constexpr int H_DIM   = 128;
constexpr int G3      = 3 * H_DIM;   // 384
constexpr int E_EDGES = 800000;
constexpr int I_DIM   = 64;
constexpr float LN_EPS = 1e-5f;
constexpr int NT = (N_NODES + 31) / 32;   // 1563 node tiles of 32
constexpr int NT16 = N_NODES / 16;        // 3125 exact (50000 = 16*3125)
constexpr int SXS = 408;                  // sX row stride (elems): 816B, 16B-aligned, 2-way banks
constexpr int SHS = 136;                  // sH row stride (elems): 272B, 2-way banks

using bf16x8 = __attribute__((ext_vector_type(8))) short;
using f32x4  = __attribute__((ext_vector_type(4))) float;

static __device__ __forceinline__ float sigm(float x) { return 1.f / (1.f + __expf(-x)); }
static __device__ __forceinline__ float tanh_fast(float x) { return 2.f / (1.f + __expf(-2.f * x)) - 1.f; }
static __device__ __forceinline__ float softplus_f(float x) {
    return (x > 20.f) ? x : log1pf(__expf(x));
}
static __device__ __forceinline__ unsigned short f2bf(float f) {
    __hip_bfloat16 b = __float2bfloat16(f);   // RNE
    return *(unsigned short*)&b;
}

// ---------------- graph preprocessing ----------------

__global__ void k_zero(int* deg_out, int* deg_in, int* cursor, int* esrc) {
    for (int i = blockIdx.x * blockDim.x + threadIdx.x; i < E_EDGES; i += gridDim.x * blockDim.x) {
        esrc[i] = 0;
        if (i < N_NODES) { deg_out[i] = 0; deg_in[i] = 0; cursor[i] = 0; }
    }
}

__global__ void k_hist(const int* __restrict__ src, const int* __restrict__ dst,
                       int* __restrict__ deg_out, int* __restrict__ deg_in) {
    for (int e = blockIdx.x * blockDim.x + threadIdx.x; e < E_EDGES; e += gridDim.x * blockDim.x) {
        int s = src[e], d = dst[e];
        if (s >= 0 && s < N_NODES) atomicAdd(&deg_out[s], 1);
        if (d >= 0 && d < N_NODES) atomicAdd(&deg_in[d], 1);
    }
}

__launch_bounds__(1024)
__global__ void k_scan(const int* __restrict__ deg, int* __restrict__ offs) {
    __shared__ int wsum[16];
    __shared__ int carry;
    const int tid = threadIdx.x;
    const int lane = tid & 63, wid = tid >> 6;
    if (tid == 0) carry = 0;
    __syncthreads();
    for (int base = 0; base < N_NODES; base += 1024) {
        int i = base + tid;
        int v = (i < N_NODES) ? deg[i] : 0;
        int x = v;
        #pragma unroll
        for (int off = 1; off < 64; off <<= 1) {
            int yv = __shfl_up(x, off);
            if (lane >= off) x += yv;
        }
        if (lane == 63) wsum[wid] = x;
        __syncthreads();
        if (wid == 0 && lane < 16) {
            int s = wsum[lane];
            #pragma unroll
            for (int off = 1; off < 16; off <<= 1) {
                int yv = __shfl_up(s, off, 16);
                if (lane >= off) s += yv;
            }
            wsum[lane] = s;
        }
        __syncthreads();
        int excl = carry + (wid > 0 ? wsum[wid - 1] : 0) + x - v;
        if (i < N_NODES) offs[i] = excl;
        __syncthreads();
        if (tid == 0) carry += wsum[15];
        __syncthreads();
    }
    if (tid == 0) offs[N_NODES] = carry;
}

__global__ void k_scatter(const int* __restrict__ src, const int* __restrict__ dst,
                          const int* __restrict__ offs, int* __restrict__ cursor,
                          int* __restrict__ esrc) {
    for (int e = blockIdx.x * blockDim.x + threadIdx.x; e < E_EDGES; e += gridDim.x * blockDim.x) {
        int d = dst[e];
        if (d < 0 || d >= N_NODES) continue;
        int pos = offs[d] + atomicAdd(&cursor[d], 1);
        if (pos >= 0 && pos < E_EDGES) esrc[pos] = src[e];
    }
}

// ---------------- GRU via MFMA ----------------
// 8 waves = 8 disjoint 16-feature slices. Round 5: LDS 46.6->34.8 KB
// (single-buffer sH with write-after-barrier; sX stride 424->408) so 3-4
// blocks/CU fit even if usable LDS is 128KB. Grid = NT (1 tile/block).
__launch_bounds__(512, 4)
__global__ void k_gru(const float* __restrict__ actions,
                      const float* __restrict__ hidden,
                      const float* __restrict__ W_ih,
                      const float* __restrict__ W_hh,
                      const float* __restrict__ b_ih,
                      const float* __restrict__ b_hh,
                      float* __restrict__ h_out) {
    __shared__ __align__(16) unsigned short sX[32 * SXS];   // 25.5 KB
    __shared__ __align__(16) unsigned short sH[32 * SHS];   // 8.5 KB

    const int tid  = threadIdx.x;
    const int w    = tid >> 6;       // 0..7: feature slice
    const int lane = tid & 63;
    const int quad = lane >> 4;
    const int l16  = lane & 15;
    const int j    = 16 * w + l16;   // output feature column, 0..127

    // B fragments: gate gt in {r,z,n}; rows gt*128 + j of W_hh / W_ih
    bf16x8 Bhh[3][4];
    #pragma unroll
    for (int gt = 0; gt < 3; ++gt) {
        const float* rowp = W_hh + (size_t)(gt * H_DIM + j) * H_DIM;
        #pragma unroll
        for (int kc = 0; kc < 4; ++kc) {
            const float* p = rowp + kc * 32 + quad * 8;
            float4 f0 = *(const float4*)p;
            float4 f1 = *(const float4*)(p + 4);
            bf16x8 v;
            v[0] = f2bf(f0.x); v[1] = f2bf(f0.y); v[2] = f2bf(f0.z); v[3] = f2bf(f0.w);
            v[4] = f2bf(f1.x); v[5] = f2bf(f1.y); v[6] = f2bf(f1.z); v[7] = f2bf(f1.w);
            Bhh[gt][kc] = v;
        }
    }
    bf16x8 Bih[3];
    #pragma unroll
    for (int gt = 0; gt < 3; ++gt) {
        bf16x8 v;
        #pragma unroll
        for (int q = 0; q < 8; ++q) v[q] = 0;
        if (quad < 2) {
            const float* p = W_ih + (size_t)(gt * H_DIM + j) * A_DIM + quad * 8;
            float4 f0 = *(const float4*)p;
            float4 f1 = *(const float4*)(p + 4);
            v[0] = f2bf(f0.x); v[1] = f2bf(f0.y); v[2] = f2bf(f0.z); v[3] = f2bf(f0.w);
            v[4] = f2bf(f1.x); v[5] = f2bf(f1.y); v[6] = f2bf(f1.z); v[7] = f2bf(f1.w);
        }
        Bih[gt] = v;
    }
    const float br   = b_ih[j] + b_hh[j];
    const float bz   = b_ih[H_DIM + j] + b_hh[H_DIM + j];
    const float bn_i = b_ih[2 * H_DIM + j];
    const float bn_h = b_hh[2 * H_DIM + j];

    const f32x4 z4 = {0.f, 0.f, 0.f, 0.f};

    for (int tile = blockIdx.x; tile < NT; tile += gridDim.x) {
        const int base = tile * 32;
        for (int idx = tid; idx < 32 * SXS; idx += 512) {
            int nl = idx / SXS, p = idx - nl * SXS;
            int n = base + nl;
            float f = (p < 400 && n < N_NODES) ? actions[(size_t)n * 400 + p] : 0.f;
            sX[nl * SXS + p] = f2bf(f);
        }
        for (int idx = tid; idx < 32 * H_DIM; idx += 512) {
            int nl = idx >> 7, k = idx & 127;
            int n = base + nl;
            sH[nl * SHS + k] = f2bf((n < N_NODES) ? hidden[(size_t)n * H_DIM + k] : 0.f);
        }
        float hp[2][4];
        #pragma unroll
        for (int m = 0; m < 2; ++m)
            #pragma unroll
            for (int r = 0; r < 4; ++r) {
                int n = base + m * 16 + quad * 4 + r;
                hp[m][r] = (n < N_NODES) ? hidden[(size_t)n * H_DIM + j] : 0.f;
            }
        __syncthreads();

        for (int t = 0; t < T_STEPS; ++t) {
            #pragma unroll
            for (int m = 0; m < 2; ++m) {
                bf16x8 ax = *(const bf16x8*)&sX[(m * 16 + l16) * SXS + t * 16 + quad * 8];
                if (quad >= 2) {
                    #pragma unroll
                    for (int q = 0; q < 8; ++q) ax[q] = 0;
                }
                f32x4 Cr = __builtin_amdgcn_mfma_f32_16x16x32_bf16(ax, Bih[0], z4, 0, 0, 0);
                f32x4 Cz = __builtin_amdgcn_mfma_f32_16x16x32_bf16(ax, Bih[1], z4, 0, 0, 0);
                f32x4 Cn = __builtin_amdgcn_mfma_f32_16x16x32_bf16(ax, Bih[2], z4, 0, 0, 0);
                f32x4 Ch = z4;
                #pragma unroll
                for (int kc = 0; kc < 4; ++kc) {
                    bf16x8 ah = *(const bf16x8*)&sH[(m * 16 + l16) * SHS + kc * 32 + quad * 8];
                    Cr = __builtin_amdgcn_mfma_f32_16x16x32_bf16(ah, Bhh[0][kc], Cr, 0, 0, 0);
                    Cz = __builtin_amdgcn_mfma_f32_16x16x32_bf16(ah, Bhh[1][kc], Cz, 0, 0, 0);
                    Ch = __builtin_amdgcn_mfma_f32_16x16x32_bf16(ah, Bhh[2][kc], Ch, 0, 0, 0);
                }
                #pragma unroll
                for (int r = 0; r < 4; ++r) {
                    float rg = sigm(Cr[r] + br);
                    float zg = sigm(Cz[r] + bz);
                    float ng = tanh_fast(Cn[r] + bn_i + rg * (Ch[r] + bn_h));
                    hp[m][r] = ng + zg * (hp[m][r] - ng);
                }
            }
            if (t < T_STEPS - 1) {
                __syncthreads();   // all reads of step t done
                #pragma unroll
                for (int m = 0; m < 2; ++m)
                    #pragma unroll
                    for (int r = 0; r < 4; ++r)
                        sH[(m * 16 + quad * 4 + r) * SHS + j] = f2bf(hp[m][r]);
                __syncthreads();   // writes visible for step t+1
            }
        }
        #pragma unroll
        for (int m = 0; m < 2; ++m)
            #pragma unroll
            for (int r = 0; r < 4; ++r) {
                int n = base + m * 16 + quad * 4 + r;
                if (n < N_NODES) h_out[(size_t)n * H_DIM + j] = hp[m][r];
            }
        __syncthreads();
    }
}

// ---------------- per-node LN stats packed: pqr[n] = {inv*ns, mu*inv*ns, ns, 0} ----------------
__global__ void k_stats(const float* __restrict__ h, const int* __restrict__ deg_out,
                        float4* __restrict__ pqr) {
    int n = blockIdx.x * (blockDim.x >> 6) + (threadIdx.x >> 6);
    int lane = threadIdx.x & 63;
    if (n >= N_NODES) return;
    float v0 = h[(size_t)n * H_DIM + lane];
    float v1 = h[(size_t)n * H_DIM + 64 + lane];
    float s = v0 + v1, qq = v0 * v0 + v1 * v1;
    #pragma unroll
    for (int m = 32; m; m >>= 1) { s += __shfl_xor(s, m); qq += __shfl_xor(qq, m); }
    float mu = s * (1.f / H_DIM);
    float var = fmaxf(qq * (1.f / H_DIM) - mu * mu, 0.f);
    float inv = rsqrtf(var + LN_EPS);
    int d = deg_out[n];
    float ns = rsqrtf((float)(d > 0 ? d : 1));
    if (lane == 0) pqr[n] = make_float4(inv * ns, mu * inv * ns, ns, 0.f);
}

// ---------------- fold Wg into the 4 heads: W_comb[r][k] = sum_c Wg[k][c]*Wh[r][c] ----------------
// b_comb[r] = sum_c Wh[r][c]*bg[c] + bh[r].  Rows: [ig_mu | ig_std | ia_mu | ia_std]
__global__ void k_comb(const float* __restrict__ Wg, const float* __restrict__ bg,
                       const float* __restrict__ Wig_mu, const float* __restrict__ big_mu,
                       const float* __restrict__ Wig_std, const float* __restrict__ big_std,
                       const float* __restrict__ Wia_mu, const float* __restrict__ bia_mu,
                       const float* __restrict__ Wia_std, const float* __restrict__ bia_std,
                       unsigned short* __restrict__ Wcomb, float* __restrict__ bcomb) {
    const int r = blockIdx.x;      // 0..255
    const int t = threadIdx.x;     // 0..127 (= k)
    const int rr = r & 63;
    const float* Wh; const float* bh;
    switch (r >> 6) {
        case 0:  Wh = Wig_mu;  bh = big_mu;  break;
        case 1:  Wh = Wig_std; bh = big_std; break;
        case 2:  Wh = Wia_mu;  bh = bia_mu;  break;
        default: Wh = Wia_std; bh = bia_std; break;
    }
    __shared__ float sWr[H_DIM];
    sWr[t] = Wh[(size_t)rr * H_DIM + t];
    __syncthreads();
    const float4* wrow = (const float4*)(Wg + (size_t)t * H_DIM);
    float acc = 0.f;
    #pragma unroll 8
    for (int c4 = 0; c4 < 32; ++c4) {
        float4 v = wrow[c4];
        acc = fmaf(v.x, sWr[4 * c4    ], acc);
        acc = fmaf(v.y, sWr[4 * c4 + 1], acc);
        acc = fmaf(v.z, sWr[4 * c4 + 2], acc);
        acc = fmaf(v.w, sWr[4 * c4 + 3], acc);
    }
    Wcomb[r * H_DIM + t] = f2bf(acc);
    if (t == 0) {
        float s = bh[rr];
        for (int c = 0; c < H_DIM; ++c) s = fmaf(bg[c], sWr[c], s);
        bcomb[r] = s;
    }
}

// ---------------- fused: edge aggregation (wave/node) + MFMA combined-head GEMM ----------------
// phase 1: y[n][j] = (g_j*(sum_e p_s*h[s][j] - sum_e q_s) + b_j*sum_e r_s)*nd  -> LDS bf16
// phase 2: out[n][r] = y[n] . W_comb[r] + b_comb[r]  (softplus on std heads)
__launch_bounds__(256)
__global__ void k_fused(const float* __restrict__ h,
                        const int* __restrict__ offs, const int* __restrict__ esrc,
                        const float4* __restrict__ pqr,
                        const float* __restrict__ ln_g, const float* __restrict__ ln_b,
                        const unsigned short* __restrict__ Wcomb,
                        const float* __restrict__ bcomb,
                        float* __restrict__ out) {
    // 16 rows x 136 ushorts (272 B rows: stride 17*16B -> ds_read_b128 only 2-way conflicts)
    __shared__ __align__(16) unsigned short yl[16][136];

    const int tid  = threadIdx.x;
    const int w    = tid >> 6;       // wave 0..3
    const int lane = tid & 63;
    const int l16  = lane & 15;
    const int quad = lane >> 4;
    const long long NI = (long long)N_NODES * I_DIM;

    // persistent B fragments: wave w owns col-tiles 4w..4w+3 (cols (4w+ct)*16+l16)
    bf16x8 B[4][4];
    float bc[4];
    #pragma unroll
    for (int ct = 0; ct < 4; ++ct) {
        int col = (w * 4 + ct) * 16 + l16;
        bc[ct] = bcomb[col];
        #pragma unroll
        for (int kc = 0; kc < 4; ++kc)
            B[ct][kc] = *(const bf16x8*)&Wcomb[col * H_DIM + kc * 32 + quad * 8];
    }
    const float2 g2 = *(const float2*)&ln_g[2 * lane];
    const float2 b2 = *(const float2*)&ln_b[2 * lane];

    for (int tile = blockIdx.x; tile < NT16; tile += gridDim.x) {
        const int base = tile * 16;
        // ---- phase 1: each wave aggregates 4 nodes; lane covers features 2*lane, 2*lane+1 ----
        #pragma unroll
        for (int i = 0; i < 4; ++i) {
            const int nl = w * 4 + i;
            const int n  = base + nl;
            const int s0 = offs[n], s1 = offs[n + 1];
            float ax = 0.f, ay = 0.f, sq = 0.f, sr = 0.f;
            for (int e0 = s0; e0 < s1; e0 += 64) {
                int sv = (e0 + lane < s1) ? esrc[e0 + lane] : 0;
                const int cnt = min(64, s1 - e0);
                for (int k = 0; k < cnt; ++k) {
                    int s = __shfl(sv, k);
                    float4 P = pqr[s];                                   // 16B broadcast
                    float2 hv = *(const float2*)&h[(size_t)s * H_DIM + 2 * lane];
                    ax = fmaf(P.x, hv.x, ax);
                    ay = fmaf(P.x, hv.y, ay);
                    sq += P.y; sr += P.z;
                }
            }
            const int d = s1 - s0;
            const float nd = rsqrtf((float)(d > 0 ? d : 1));
            float y0 = (g2.x * (ax - sq) + b2.x * sr) * nd;
            float y1 = (g2.y * (ay - sq) + b2.y * sr) * nd;
            unsigned int pk = ((unsigned int)f2bf(y1) << 16) | (unsigned int)f2bf(y0);
            *(unsigned int*)&yl[nl][2 * lane] = pk;
        }
        __syncthreads();
        // ---- phase 2: MFMA 16x128 @ 128x256 ----
        bf16x8 A[4];
        #pragma unroll
        for (int kc = 0; kc < 4; ++kc)
            A[kc] = *(const bf16x8*)&yl[l16][kc * 32 + quad * 8];
        #pragma unroll
        for (int ct = 0; ct < 4; ++ct) {
            f32x4 C = {0.f, 0.f, 0.f, 0.f};
            #pragma unroll
            for (int kc = 0; kc < 4; ++kc)
                C = __builtin_amdgcn_mfma_f32_16x16x32_bf16(A[kc], B[ct][kc], C, 0, 0, 0);
            const int col  = (w * 4 + ct) * 16 + l16;
            const int head = col >> 6;
            const int wi   = col & 63;
            const bool sp  = (col & 64) != 0;
            #pragma unroll
            for (int r_ = 0; r_ < 4; ++r_) {
                const int node = base + quad * 4 + r_;
                float v = C[r_] + bc[ct];
                if (sp) v = softplus_f(v);
                out[(long long)head * NI + (long long)node * I_DIM + wi] = v;
            }
        }
        __syncthreads();
    }
}

extern "C" void kernel_launch(void* const* d_in, const int* in_sizes, int n_in,
                              void* d_out, int out_size, void* d_ws, size_t ws_size,
                              hipStream_t stream) {
    const float* actions = (const float*)d_in[0];
    const float* hidden  = (const float*)d_in[1];
    const int*   src     = (const int*)d_in[2];
    const int*   dst     = (const int*)d_in[3];
    const float* W_ih    = (const float*)d_in[4];
    const float* W_hh    = (const float*)d_in[5];
    const float* b_ih    = (const float*)d_in[6];
    const float* b_hh    = (const float*)d_in[7];
    const float* ln_g    = (const float*)d_in[8];
    const float* ln_b    = (const float*)d_in[9];
    const float* Wg      = (const float*)d_in[10];
    const float* bg      = (const float*)d_in[11];
    const float* Wia_mu  = (const float*)d_in[12];
    const float* bia_mu  = (const float*)d_in[13];
    const float* Wia_std = (const float*)d_in[14];
    const float* bia_std = (const float*)d_in[15];
    const float* Wig_mu  = (const float*)d_in[16];
    const float* big_mu  = (const float*)d_in[17];
    const float* Wig_std = (const float*)d_in[18];
    const float* big_std = (const float*)d_in[19];
    float* out = (float*)d_out;

    // ws layout — total ~4.87 MB
    char* w = (char*)d_ws;
    const size_t SZN = 200064;               // N ints, padded to 64
    int*   deg_out = (int*)(w);
    int*   deg_in  = (int*)(w + SZN);
    int*   offs    = (int*)(w + 2 * SZN);    // N+1 ints within padded slot
    int*   cursor  = (int*)(w + 2 * SZN + 200128);
    int*   esrc    = (int*)(w + 3 * SZN + 200128);                       // E ints = 3.2 MB
    float4* pqrA   = (float4*)(w + 3 * SZN + 200128 + 3200000);          // N*16 B = 800 KB (16B aligned)
    unsigned short* Wcomb = (unsigned short*)(w + 3 * SZN + 200128 + 3200000 + 800000);  // 64 KB
    float* bcomb   = (float*)(w + 3 * SZN + 200128 + 3200000 + 800000 + 65536);          // 1 KB
    // end = 600192 + 200128 + 3200000 + 800000 + 65536 + 1024 = 4,866,880 B

    k_zero<<<2048, 256, 0, stream>>>(deg_out, deg_in, cursor, esrc);
    k_hist<<<1024, 256, 0, stream>>>(src, dst, deg_out, deg_in);
    k_scan<<<1, 1024, 0, stream>>>(deg_in, offs);
    k_scatter<<<1024, 256, 0, stream>>>(src, dst, offs, cursor, esrc);
    k_comb<<<256, 128, 0, stream>>>(Wg, bg, Wig_mu, big_mu, Wig_std, big_std,
                                    Wia_mu, bia_mu, Wia_std, bia_std, Wcomb, bcomb);

    // GRU writes f32 h directly into out section 4 (element offset 4*N*I)
    float* h_f = out + (size_t)4 * N_NODES * I_DIM;
    k_gru<<<NT, 512, 0, stream>>>(actions, hidden, W_ih, W_hh, b_ih, b_hh, h_f);

    k_stats<<<(N_NODES + 3) / 4, 256, 0, stream>>>(h_f, deg_out, pqrA);

    k_fused<<<2048, 256, 0, stream>>>(h_f, offs, esrc, pqrA, ln_g, ln_b,
                                      Wcomb, bcomb, out);
}

// Round 6
// 753.623 us; speedup vs baseline: 1.4874x; 1.1810x over previous
//
#include <hip/hip_runtime.h>
#include <hip/hip_bf16.h>
#include <math.h>

constexpr int N_NODES = 50000;
constexpr int T_STEPS = 25;
constexpr int A_DIM   = 16;
constexpr int H_DIM   = 128;
constexpr int G3      = 3 * H_DIM;   // 384
constexpr int E_EDGES = 800000;
constexpr int I_DIM   = 64;
constexpr float LN_EPS = 1e-5f;
constexpr int NT = (N_NODES + 31) / 32;   // 1563 node tiles of 32
constexpr int NT16 = N_NODES / 16;        // 3125 exact (50000 = 16*3125)
constexpr int SXS = 408;                  // sX row stride (elems): 816B, 16B-aligned, 2-way banks
constexpr int SHS = 136;                  // sH row stride (elems): 272B, 2-way banks

using bf16x8 = __attribute__((ext_vector_type(8))) short;
using f32x4  = __attribute__((ext_vector_type(4))) float;

// v_rcp_f32: 1 transcendental inst, ~1ulp. Replaces IEEE divide sequence
// (v_div_scale/fmas/fixup ~11 inst) — the round-5 VALU hog (3 divides/output).
static __device__ __forceinline__ float fast_rcp(float x) { return __builtin_amdgcn_rcpf(x); }
static __device__ __forceinline__ float sigm(float x) { return fast_rcp(1.f + __expf(-x)); }
static __device__ __forceinline__ float tanh_fast(float x) {
    return fmaf(2.f, fast_rcp(1.f + __expf(-2.f * x)), -1.f);
}
static __device__ __forceinline__ float softplus_f(float x) {
    return (x > 20.f) ? x : __logf(1.f + __expf(x));
}
static __device__ __forceinline__ unsigned short f2bf(float f) {
    __hip_bfloat16 b = __float2bfloat16(f);   // RNE
    return *(unsigned short*)&b;
}

// ---------------- graph preprocessing ----------------

__global__ void k_zero(int* deg_out, int* deg_in, int* cursor, int* esrc) {
    for (int i = blockIdx.x * blockDim.x + threadIdx.x; i < E_EDGES; i += gridDim.x * blockDim.x) {
        esrc[i] = 0;
        if (i < N_NODES) { deg_out[i] = 0; deg_in[i] = 0; cursor[i] = 0; }
    }
}

__global__ void k_hist(const int* __restrict__ src, const int* __restrict__ dst,
                       int* __restrict__ deg_out, int* __restrict__ deg_in) {
    for (int e = blockIdx.x * blockDim.x + threadIdx.x; e < E_EDGES; e += gridDim.x * blockDim.x) {
        int s = src[e], d = dst[e];
        if (s >= 0 && s < N_NODES) atomicAdd(&deg_out[s], 1);
        if (d >= 0 && d < N_NODES) atomicAdd(&deg_in[d], 1);
    }
}

__launch_bounds__(1024)
__global__ void k_scan(const int* __restrict__ deg, int* __restrict__ offs) {
    __shared__ int wsum[16];
    __shared__ int carry;
    const int tid = threadIdx.x;
    const int lane = tid & 63, wid = tid >> 6;
    if (tid == 0) carry = 0;
    __syncthreads();
    for (int base = 0; base < N_NODES; base += 1024) {
        int i = base + tid;
        int v = (i < N_NODES) ? deg[i] : 0;
        int x = v;
        #pragma unroll
        for (int off = 1; off < 64; off <<= 1) {
            int yv = __shfl_up(x, off);
            if (lane >= off) x += yv;
        }
        if (lane == 63) wsum[wid] = x;
        __syncthreads();
        if (wid == 0 && lane < 16) {
            int s = wsum[lane];
            #pragma unroll
            for (int off = 1; off < 16; off <<= 1) {
                int yv = __shfl_up(s, off, 16);
                if (lane >= off) s += yv;
            }
            wsum[lane] = s;
        }
        __syncthreads();
        int excl = carry + (wid > 0 ? wsum[wid - 1] : 0) + x - v;
        if (i < N_NODES) offs[i] = excl;
        __syncthreads();
        if (tid == 0) carry += wsum[15];
        __syncthreads();
    }
    if (tid == 0) offs[N_NODES] = carry;
}

__global__ void k_scatter(const int* __restrict__ src, const int* __restrict__ dst,
                          const int* __restrict__ offs, int* __restrict__ cursor,
                          int* __restrict__ esrc) {
    for (int e = blockIdx.x * blockDim.x + threadIdx.x; e < E_EDGES; e += gridDim.x * blockDim.x) {
        int d = dst[e];
        if (d < 0 || d >= N_NODES) continue;
        int pos = offs[d] + atomicAdd(&cursor[d], 1);
        if (pos >= 0 && pos < E_EDGES) esrc[pos] = src[e];
    }
}

// ---------------- GRU via MFMA ----------------
// 8 waves = 8 disjoint 16-feature slices. Round 6: v_rcp gates (was IEEE
// divide sequences — the VALU hog), biases folded into MFMA C-init.
__launch_bounds__(512, 4)
__global__ void k_gru(const float* __restrict__ actions,
                      const float* __restrict__ hidden,
                      const float* __restrict__ W_ih,
                      const float* __restrict__ W_hh,
                      const float* __restrict__ b_ih,
                      const float* __restrict__ b_hh,
                      float* __restrict__ h_out) {
    __shared__ __align__(16) unsigned short sX[32 * SXS];   // 25.5 KB
    __shared__ __align__(16) unsigned short sH[32 * SHS];   // 8.5 KB

    const int tid  = threadIdx.x;
    const int w    = tid >> 6;       // 0..7: feature slice
    const int lane = tid & 63;
    const int quad = lane >> 4;
    const int l16  = lane & 15;
    const int j    = 16 * w + l16;   // output feature column, 0..127

    // B fragments: gate gt in {r,z,n}; rows gt*128 + j of W_hh / W_ih
    bf16x8 Bhh[3][4];
    #pragma unroll
    for (int gt = 0; gt < 3; ++gt) {
        const float* rowp = W_hh + (size_t)(gt * H_DIM + j) * H_DIM;
        #pragma unroll
        for (int kc = 0; kc < 4; ++kc) {
            const float* p = rowp + kc * 32 + quad * 8;
            float4 f0 = *(const float4*)p;
            float4 f1 = *(const float4*)(p + 4);
            bf16x8 v;
            v[0] = f2bf(f0.x); v[1] = f2bf(f0.y); v[2] = f2bf(f0.z); v[3] = f2bf(f0.w);
            v[4] = f2bf(f1.x); v[5] = f2bf(f1.y); v[6] = f2bf(f1.z); v[7] = f2bf(f1.w);
            Bhh[gt][kc] = v;
        }
    }
    bf16x8 Bih[3];
    #pragma unroll
    for (int gt = 0; gt < 3; ++gt) {
        bf16x8 v;
        #pragma unroll
        for (int q = 0; q < 8; ++q) v[q] = 0;
        if (quad < 2) {
            const float* p = W_ih + (size_t)(gt * H_DIM + j) * A_DIM + quad * 8;
            float4 f0 = *(const float4*)p;
            float4 f1 = *(const float4*)(p + 4);
            v[0] = f2bf(f0.x); v[1] = f2bf(f0.y); v[2] = f2bf(f0.z); v[3] = f2bf(f0.w);
            v[4] = f2bf(f1.x); v[5] = f2bf(f1.y); v[6] = f2bf(f1.z); v[7] = f2bf(f1.w);
        }
        Bih[gt] = v;
    }
    const float br   = b_ih[j] + b_hh[j];
    const float bz   = b_ih[H_DIM + j] + b_hh[H_DIM + j];
    const float bn_i = b_ih[2 * H_DIM + j];
    const float bn_h = b_hh[2 * H_DIM + j];
    // bias-folded accumulator inits (all 4 C rows share column j's bias)
    const f32x4 cr0 = {br, br, br, br};
    const f32x4 cz0 = {bz, bz, bz, bz};
    const f32x4 cn0 = {bn_i, bn_i, bn_i, bn_i};
    const f32x4 ch0 = {bn_h, bn_h, bn_h, bn_h};

    for (int tile = blockIdx.x; tile < NT; tile += gridDim.x) {
        const int base = tile * 32;
        for (int idx = tid; idx < 32 * SXS; idx += 512) {
            int nl = idx / SXS, p = idx - nl * SXS;
            int n = base + nl;
            float f = (p < 400 && n < N_NODES) ? actions[(size_t)n * 400 + p] : 0.f;
            sX[nl * SXS + p] = f2bf(f);
        }
        for (int idx = tid; idx < 32 * H_DIM; idx += 512) {
            int nl = idx >> 7, k = idx & 127;
            int n = base + nl;
            sH[nl * SHS + k] = f2bf((n < N_NODES) ? hidden[(size_t)n * H_DIM + k] : 0.f);
        }
        float hp[2][4];
        #pragma unroll
        for (int m = 0; m < 2; ++m)
            #pragma unroll
            for (int r = 0; r < 4; ++r) {
                int n = base + m * 16 + quad * 4 + r;
                hp[m][r] = (n < N_NODES) ? hidden[(size_t)n * H_DIM + j] : 0.f;
            }
        __syncthreads();

        for (int t = 0; t < T_STEPS; ++t) {
            #pragma unroll
            for (int m = 0; m < 2; ++m) {
                bf16x8 ax = *(const bf16x8*)&sX[(m * 16 + l16) * SXS + t * 16 + quad * 8];
                if (quad >= 2) {
                    #pragma unroll
                    for (int q = 0; q < 8; ++q) ax[q] = 0;
                }
                f32x4 Cr = __builtin_amdgcn_mfma_f32_16x16x32_bf16(ax, Bih[0], cr0, 0, 0, 0);
                f32x4 Cz = __builtin_amdgcn_mfma_f32_16x16x32_bf16(ax, Bih[1], cz0, 0, 0, 0);
                f32x4 Cn = __builtin_amdgcn_mfma_f32_16x16x32_bf16(ax, Bih[2], cn0, 0, 0, 0);
                f32x4 Ch = ch0;
                #pragma unroll
                for (int kc = 0; kc < 4; ++kc) {
                    bf16x8 ah = *(const bf16x8*)&sH[(m * 16 + l16) * SHS + kc * 32 + quad * 8];
                    Cr = __builtin_amdgcn_mfma_f32_16x16x32_bf16(ah, Bhh[0][kc], Cr, 0, 0, 0);
                    Cz = __builtin_amdgcn_mfma_f32_16x16x32_bf16(ah, Bhh[1][kc], Cz, 0, 0, 0);
                    Ch = __builtin_amdgcn_mfma_f32_16x16x32_bf16(ah, Bhh[2][kc], Ch, 0, 0, 0);
                }
                #pragma unroll
                for (int r = 0; r < 4; ++r) {
                    float rg = sigm(Cr[r]);
                    float zg = sigm(Cz[r]);
                    float ng = tanh_fast(Cn[r] + rg * Ch[r]);
                    hp[m][r] = ng + zg * (hp[m][r] - ng);
                }
            }
            if (t < T_STEPS - 1) {
                __syncthreads();   // all reads of step t done
                #pragma unroll
                for (int m = 0; m < 2; ++m)
                    #pragma unroll
                    for (int r = 0; r < 4; ++r)
                        sH[(m * 16 + quad * 4 + r) * SHS + j] = f2bf(hp[m][r]);
                __syncthreads();   // writes visible for step t+1
            }
        }
        #pragma unroll
        for (int m = 0; m < 2; ++m)
            #pragma unroll
            for (int r = 0; r < 4; ++r) {
                int n = base + m * 16 + quad * 4 + r;
                if (n < N_NODES) h_out[(size_t)n * H_DIM + j] = hp[m][r];
            }
        __syncthreads();
    }
}

// ---------------- per-node LN stats packed: pqr[n] = {inv*ns, mu*inv*ns, ns, 0} ----------------
__global__ void k_stats(const float* __restrict__ h, const int* __restrict__ deg_out,
                        float4* __restrict__ pqr) {
    int n = blockIdx.x * (blockDim.x >> 6) + (threadIdx.x >> 6);
    int lane = threadIdx.x & 63;
    if (n >= N_NODES) return;
    float v0 = h[(size_t)n * H_DIM + lane];
    float v1 = h[(size_t)n * H_DIM + 64 + lane];
    float s = v0 + v1, qq = v0 * v0 + v1 * v1;
    #pragma unroll
    for (int m = 32; m; m >>= 1) { s += __shfl_xor(s, m); qq += __shfl_xor(qq, m); }
    float mu = s * (1.f / H_DIM);
    float var = fmaxf(qq * (1.f / H_DIM) - mu * mu, 0.f);
    float inv = rsqrtf(var + LN_EPS);
    int d = deg_out[n];
    float ns = rsqrtf((float)(d > 0 ? d : 1));
    if (lane == 0) pqr[n] = make_float4(inv * ns, mu * inv * ns, ns, 0.f);
}

// ---------------- fold Wg into the 4 heads: W_comb[r][k] = sum_c Wg[k][c]*Wh[r][c] ----------------
// b_comb[r] = sum_c Wh[r][c]*bg[c] + bh[r].  Rows: [ig_mu | ig_std | ia_mu | ia_std]
__global__ void k_comb(const float* __restrict__ Wg, const float* __restrict__ bg,
                       const float* __restrict__ Wig_mu, const float* __restrict__ big_mu,
                       const float* __restrict__ Wig_std, const float* __restrict__ big_std,
                       const float* __restrict__ Wia_mu, const float* __restrict__ bia_mu,
                       const float* __restrict__ Wia_std, const float* __restrict__ bia_std,
                       unsigned short* __restrict__ Wcomb, float* __restrict__ bcomb) {
    const int r = blockIdx.x;      // 0..255
    const int t = threadIdx.x;     // 0..127 (= k)
    const int rr = r & 63;
    const float* Wh; const float* bh;
    switch (r >> 6) {
        case 0:  Wh = Wig_mu;  bh = big_mu;  break;
        case 1:  Wh = Wig_std; bh = big_std; break;
        case 2:  Wh = Wia_mu;  bh = bia_mu;  break;
        default: Wh = Wia_std; bh = bia_std; break;
    }
    __shared__ float sWr[H_DIM];
    sWr[t] = Wh[(size_t)rr * H_DIM + t];
    __syncthreads();
    const float4* wrow = (const float4*)(Wg + (size_t)t * H_DIM);
    float acc = 0.f;
    #pragma unroll 8
    for (int c4 = 0; c4 < 32; ++c4) {
        float4 v = wrow[c4];
        acc = fmaf(v.x, sWr[4 * c4    ], acc);
        acc = fmaf(v.y, sWr[4 * c4 + 1], acc);
        acc = fmaf(v.z, sWr[4 * c4 + 2], acc);
        acc = fmaf(v.w, sWr[4 * c4 + 3], acc);
    }
    Wcomb[r * H_DIM + t] = f2bf(acc);
    if (t == 0) {
        float s = bh[rr];
        for (int c = 0; c < H_DIM; ++c) s = fmaf(bg[c], sWr[c], s);
        bcomb[r] = s;
    }
}

// ---------------- fused: edge aggregation (wave/node) + MFMA combined-head GEMM ----------------
// phase 1: y[n][j] = (g_j*(sum_e p_s*h[s][j] - sum_e q_s) + b_j*sum_e r_s)*nd  -> LDS bf16
// phase 2: out[n][r] = y[n] . W_comb[r] + b_comb[r]  (softplus on std heads)
__launch_bounds__(256)
__global__ void k_fused(const float* __restrict__ h,
                        const int* __restrict__ offs, const int* __restrict__ esrc,
                        const float4* __restrict__ pqr,
                        const float* __restrict__ ln_g, const float* __restrict__ ln_b,
                        const unsigned short* __restrict__ Wcomb,
                        const float* __restrict__ bcomb,
                        float* __restrict__ out) {
    // 16 rows x 136 ushorts (272 B rows: stride 17*16B -> ds_read_b128 only 2-way conflicts)
    __shared__ __align__(16) unsigned short yl[16][136];

    const int tid  = threadIdx.x;
    const int w    = tid >> 6;       // wave 0..3
    const int lane = tid & 63;
    const int l16  = lane & 15;
    const int quad = lane >> 4;
    const long long NI = (long long)N_NODES * I_DIM;

    // persistent B fragments: wave w owns col-tiles 4w..4w+3 (cols (4w+ct)*16+l16)
    bf16x8 B[4][4];
    float bc[4];
    #pragma unroll
    for (int ct = 0; ct < 4; ++ct) {
        int col = (w * 4 + ct) * 16 + l16;
        bc[ct] = bcomb[col];
        #pragma unroll
        for (int kc = 0; kc < 4; ++kc)
            B[ct][kc] = *(const bf16x8*)&Wcomb[col * H_DIM + kc * 32 + quad * 8];
    }
    const float2 g2 = *(const float2*)&ln_g[2 * lane];
    const float2 b2 = *(const float2*)&ln_b[2 * lane];

    for (int tile = blockIdx.x; tile < NT16; tile += gridDim.x) {
        const int base = tile * 16;
        // ---- phase 1: each wave aggregates 4 nodes; lane covers features 2*lane, 2*lane+1 ----
        #pragma unroll
        for (int i = 0; i < 4; ++i) {
            const int nl = w * 4 + i;
            const int n  = base + nl;
            const int s0 = offs[n], s1 = offs[n + 1];
            float ax = 0.f, ay = 0.f, sq = 0.f, sr = 0.f;
            for (int e0 = s0; e0 < s1; e0 += 64) {
                int sv = (e0 + lane < s1) ? esrc[e0 + lane] : 0;
                const int cnt = min(64, s1 - e0);
                for (int k = 0; k < cnt; ++k) {
                    int s = __shfl(sv, k);
                    float4 P = pqr[s];                                   // 16B broadcast
                    float2 hv = *(const float2*)&h[(size_t)s * H_DIM + 2 * lane];
                    ax = fmaf(P.x, hv.x, ax);
                    ay = fmaf(P.x, hv.y, ay);
                    sq += P.y; sr += P.z;
                }
            }
            const int d = s1 - s0;
            const float nd = rsqrtf((float)(d > 0 ? d : 1));
            float y0 = (g2.x * (ax - sq) + b2.x * sr) * nd;
            float y1 = (g2.y * (ay - sq) + b2.y * sr) * nd;
            unsigned int pk = ((unsigned int)f2bf(y1) << 16) | (unsigned int)f2bf(y0);
            *(unsigned int*)&yl[nl][2 * lane] = pk;
        }
        __syncthreads();
        // ---- phase 2: MFMA 16x128 @ 128x256 ----
        bf16x8 A[4];
        #pragma unroll
        for (int kc = 0; kc < 4; ++kc)
            A[kc] = *(const bf16x8*)&yl[l16][kc * 32 + quad * 8];
        #pragma unroll
        for (int ct = 0; ct < 4; ++ct) {
            f32x4 C = {0.f, 0.f, 0.f, 0.f};
            #pragma unroll
            for (int kc = 0; kc < 4; ++kc)
                C = __builtin_amdgcn_mfma_f32_16x16x32_bf16(A[kc], B[ct][kc], C, 0, 0, 0);
            const int col  = (w * 4 + ct) * 16 + l16;
            const int head = col >> 6;
            const int wi   = col & 63;
            const bool sp  = (col & 64) != 0;
            #pragma unroll
            for (int r_ = 0; r_ < 4; ++r_) {
                const int node = base + quad * 4 + r_;
                float v = C[r_] + bc[ct];
                if (sp) v = softplus_f(v);
                out[(long long)head * NI + (long long)node * I_DIM + wi] = v;
            }
        }
        __syncthreads();
    }
}

extern "C" void kernel_launch(void* const* d_in, const int* in_sizes, int n_in,
                              void* d_out, int out_size, void* d_ws, size_t ws_size,
                              hipStream_t stream) {
    const float* actions = (const float*)d_in[0];
    const float* hidden  = (const float*)d_in[1];
    const int*   src     = (const int*)d_in[2];
    const int*   dst     = (const int*)d_in[3];
    const float* W_ih    = (const float*)d_in[4];
    const float* W_hh    = (const float*)d_in[5];
    const float* b_ih    = (const float*)d_in[6];
    const float* b_hh    = (const float*)d_in[7];
    const float* ln_g    = (const float*)d_in[8];
    const float* ln_b    = (const float*)d_in[9];
    const float* Wg      = (const float*)d_in[10];
    const float* bg      = (const float*)d_in[11];
    const float* Wia_mu  = (const float*)d_in[12];
    const float* bia_mu  = (const float*)d_in[13];
    const float* Wia_std = (const float*)d_in[14];
    const float* bia_std = (const float*)d_in[15];
    const float* Wig_mu  = (const float*)d_in[16];
    const float* big_mu  = (const float*)d_in[17];
    const float* Wig_std = (const float*)d_in[18];
    const float* big_std = (const float*)d_in[19];
    float* out = (float*)d_out;

    // ws layout — total ~4.87 MB
    char* w = (char*)d_ws;
    const size_t SZN = 200064;               // N ints, padded to 64
    int*   deg_out = (int*)(w);
    int*   deg_in  = (int*)(w + SZN);
    int*   offs    = (int*)(w + 2 * SZN);    // N+1 ints within padded slot
    int*   cursor  = (int*)(w + 2 * SZN + 200128);
    int*   esrc    = (int*)(w + 3 * SZN + 200128);                       // E ints = 3.2 MB
    float4* pqrA   = (float4*)(w + 3 * SZN + 200128 + 3200000);          // N*16 B = 800 KB (16B aligned)
    unsigned short* Wcomb = (unsigned short*)(w + 3 * SZN + 200128 + 3200000 + 800000);  // 64 KB
    float* bcomb   = (float*)(w + 3 * SZN + 200128 + 3200000 + 800000 + 65536);          // 1 KB
    // end = 600192 + 200128 + 3200000 + 800000 + 65536 + 1024 = 4,866,880 B

    k_zero<<<2048, 256, 0, stream>>>(deg_out, deg_in, cursor, esrc);
    k_hist<<<1024, 256, 0, stream>>>(src, dst, deg_out, deg_in);
    k_scan<<<1, 1024, 0, stream>>>(deg_in, offs);
    k_scatter<<<1024, 256, 0, stream>>>(src, dst, offs, cursor, esrc);
    k_comb<<<256, 128, 0, stream>>>(Wg, bg, Wig_mu, big_mu, Wig_std, big_std,
                                    Wia_mu, bia_mu, Wia_std, bia_std, Wcomb, bcomb);

    // GRU writes f32 h directly into out section 4 (element offset 4*N*I)
    float* h_f = out + (size_t)4 * N_NODES * I_DIM;
    k_gru<<<NT, 512, 0, stream>>>(actions, hidden, W_ih, W_hh, b_ih, b_hh, h_f);

    k_stats<<<(N_NODES + 3) / 4, 256, 0, stream>>>(h_f, deg_out, pqrA);

    k_fused<<<2048, 256, 0, stream>>>(h_f, offs, esrc, pqrA, ln_g, ln_b,
                                      Wcomb, bcomb, out);
}

// Round 8
// 637.399 us; speedup vs baseline: 1.7587x; 1.1823x over previous
//
#include <hip/hip_runtime.h>
#include <hip/hip_bf16.h>
#include <math.h>

constexpr int N_NODES = 50000;
constexpr int T_STEPS = 25;
constexpr int A_DIM   = 16;
constexpr int H_DIM   = 128;
constexpr int G3      = 3 * H_DIM;   // 384
constexpr int E_EDGES = 800000;
constexpr int I_DIM   = 64;
constexpr float LN_EPS = 1e-5f;
constexpr int NT = (N_NODES + 31) / 32;   // 1563 node tiles of 32
constexpr int NT16 = N_NODES / 16;        // 3125 exact (50000 = 16*3125)
constexpr int SXS = 408;                  // sX row stride (elems): 816B, 16B-aligned, 2-way banks
constexpr int SHS = 136;                  // sH row stride (elems): 272B, 2-way banks
constexpr int SCB = 196;                  // scan blocks (196*256 = 50176 >= N)

using bf16x8 = __attribute__((ext_vector_type(8))) short;
using f32x4  = __attribute__((ext_vector_type(4))) float;

static __device__ __forceinline__ float fast_rcp(float x) { return __builtin_amdgcn_rcpf(x); }
static __device__ __forceinline__ float sigm(float x) { return fast_rcp(1.f + __expf(-x)); }
static __device__ __forceinline__ float tanh_fast(float x) {
    return fmaf(2.f, fast_rcp(1.f + __expf(-2.f * x)), -1.f);
}
static __device__ __forceinline__ float softplus_f(float x) {
    return (x > 20.f) ? x : __logf(1.f + __expf(x));
}
static __device__ __forceinline__ unsigned short f2bf(float f) {
    __hip_bfloat16 b = __float2bfloat16(f);   // RNE
    return *(unsigned short*)&b;
}
// decode a uint32 holding two bf16 (low = elem0, high = elem1)
static __device__ __forceinline__ float2 bfp(unsigned int u) {
    union { unsigned int i; float f; } lo, hi;
    lo.i = u << 16; hi.i = u & 0xFFFF0000u;
    return make_float2(lo.f, hi.f);
}

// ---------------- graph preprocessing ----------------

__global__ void k_zero(int* deg_out, int* deg_in, int* cursor, int* esrc) {
    for (int i = blockIdx.x * blockDim.x + threadIdx.x; i < E_EDGES; i += gridDim.x * blockDim.x) {
        esrc[i] = 0;
        if (i < N_NODES) { deg_out[i] = 0; deg_in[i] = 0; cursor[i] = 0; }
    }
}

__global__ void k_hist(const int* __restrict__ src, const int* __restrict__ dst,
                       int* __restrict__ deg_out, int* __restrict__ deg_in) {
    for (int e = blockIdx.x * blockDim.x + threadIdx.x; e < E_EDGES; e += gridDim.x * blockDim.x) {
        int s = src[e], d = dst[e];
        if (s >= 0 && s < N_NODES) atomicAdd(&deg_out[s], 1);
        if (d >= 0 && d < N_NODES) atomicAdd(&deg_in[d], 1);
    }
}

// 3-kernel parallel scan (replaces 1-block serial scan)
__global__ void k_scan1(const int* __restrict__ deg, int* __restrict__ offs,
                        int* __restrict__ bsum) {
    __shared__ int wsum[4];
    const int tid = threadIdx.x, lane = tid & 63, wid = tid >> 6;
    const int i = blockIdx.x * 256 + tid;
    int v = (i < N_NODES) ? deg[i] : 0;
    int x = v;
    #pragma unroll
    for (int off = 1; off < 64; off <<= 1) {
        int yv = __shfl_up(x, off);
        if (lane >= off) x += yv;
    }
    if (lane == 63) wsum[wid] = x;
    __syncthreads();
    int pre = 0;
    #pragma unroll
    for (int w2 = 0; w2 < 3; ++w2) if (w2 < wid) pre += wsum[w2];
    if (i < N_NODES) offs[i] = pre + x - v;   // block-local exclusive
    if (tid == 255) bsum[blockIdx.x] = pre + x;
}

__global__ void k_scan2(const int* __restrict__ bsum, int* __restrict__ boffs,
                        int* __restrict__ offs) {
    __shared__ int wsum[4];
    const int tid = threadIdx.x, lane = tid & 63, wid = tid >> 6;
    int v = (tid < SCB) ? bsum[tid] : 0;
    int x = v;
    #pragma unroll
    for (int off = 1; off < 64; off <<= 1) {
        int yv = __shfl_up(x, off);
        if (lane >= off) x += yv;
    }
    if (lane == 63) wsum[wid] = x;
    __syncthreads();
    int pre = 0;
    #pragma unroll
    for (int w2 = 0; w2 < 3; ++w2) if (w2 < wid) pre += wsum[w2];
    if (tid < SCB) boffs[tid] = pre + x - v;
    if (tid == 255) offs[N_NODES] = pre + x;
}

__global__ void k_scan3(const int* __restrict__ boffs, int* __restrict__ offs) {
    const int i = blockIdx.x * 256 + threadIdx.x;
    if (i < N_NODES) offs[i] += boffs[blockIdx.x];
}

__global__ void k_scatter(const int* __restrict__ src, const int* __restrict__ dst,
                          const int* __restrict__ offs, int* __restrict__ cursor,
                          int* __restrict__ esrc) {
    for (int e = blockIdx.x * blockDim.x + threadIdx.x; e < E_EDGES; e += gridDim.x * blockDim.x) {
        int d = dst[e];
        if (d < 0 || d >= N_NODES) continue;
        int pos = offs[d] + atomicAdd(&cursor[d], 1);
        if (pos >= 0 && pos < E_EDGES) esrc[pos] = src[e];
    }
}

// ---------------- GRU via MFMA ----------------
// Round 8: fix round-7 epilogue OOB (tile = 1024 float4, loop was writing
// 4096 -> raced into other tiles' h_out). it<2 + idx4<1024 guard.
__launch_bounds__(512, 4)
__global__ void k_gru(const float* __restrict__ actions,
                      const float* __restrict__ hidden,
                      const float* __restrict__ W_ih,
                      const float* __restrict__ W_hh,
                      const float* __restrict__ b_ih,
                      const float* __restrict__ b_hh,
                      const float* __restrict__ ln_g,
                      const float* __restrict__ ln_b,
                      const int* __restrict__ deg_out,
                      unsigned int* __restrict__ zA,   // null -> skip z fusion
                      float* __restrict__ h_out) {
    __shared__ __align__(16) unsigned short sX[32 * SXS];   // 25.5 KB (reused as f32 staging)
    __shared__ __align__(16) unsigned short sH[32 * SHS];   // 8.5 KB

    const int tid  = threadIdx.x;
    const int w    = tid >> 6;       // 0..7: feature slice
    const int lane = tid & 63;
    const int quad = lane >> 4;
    const int l16  = lane & 15;
    const int j    = 16 * w + l16;   // output feature column, 0..127

    bf16x8 Bhh[3][4];
    #pragma unroll
    for (int gt = 0; gt < 3; ++gt) {
        const float* rowp = W_hh + (size_t)(gt * H_DIM + j) * H_DIM;
        #pragma unroll
        for (int kc = 0; kc < 4; ++kc) {
            const float* p = rowp + kc * 32 + quad * 8;
            float4 f0 = *(const float4*)p;
            float4 f1 = *(const float4*)(p + 4);
            bf16x8 v;
            v[0] = f2bf(f0.x); v[1] = f2bf(f0.y); v[2] = f2bf(f0.z); v[3] = f2bf(f0.w);
            v[4] = f2bf(f1.x); v[5] = f2bf(f1.y); v[6] = f2bf(f1.z); v[7] = f2bf(f1.w);
            Bhh[gt][kc] = v;
        }
    }
    bf16x8 Bih[3];
    #pragma unroll
    for (int gt = 0; gt < 3; ++gt) {
        bf16x8 v;
        #pragma unroll
        for (int q = 0; q < 8; ++q) v[q] = 0;
        if (quad < 2) {
            const float* p = W_ih + (size_t)(gt * H_DIM + j) * A_DIM + quad * 8;
            float4 f0 = *(const float4*)p;
            float4 f1 = *(const float4*)(p + 4);
            v[0] = f2bf(f0.x); v[1] = f2bf(f0.y); v[2] = f2bf(f0.z); v[3] = f2bf(f0.w);
            v[4] = f2bf(f1.x); v[5] = f2bf(f1.y); v[6] = f2bf(f1.z); v[7] = f2bf(f1.w);
        }
        Bih[gt] = v;
    }
    const float br   = b_ih[j] + b_hh[j];
    const float bz   = b_ih[H_DIM + j] + b_hh[H_DIM + j];
    const float bn_i = b_ih[2 * H_DIM + j];
    const float bn_h = b_hh[2 * H_DIM + j];
    const f32x4 cr0 = {br, br, br, br};
    const f32x4 cz0 = {bz, bz, bz, bz};
    const f32x4 cn0 = {bn_i, bn_i, bn_i, bn_i};
    const f32x4 ch0 = {bn_h, bn_h, bn_h, bn_h};
    const float2 lg2 = *(const float2*)&ln_g[2 * lane];
    const float2 lb2 = *(const float2*)&ln_b[2 * lane];

    for (int tile = blockIdx.x; tile < NT; tile += gridDim.x) {
        const int base = tile * 32;
        for (int idx = tid; idx < 32 * SXS; idx += 512) {
            int nl = idx / SXS, p = idx - nl * SXS;
            int n = base + nl;
            float f = (p < 400 && n < N_NODES) ? actions[(size_t)n * 400 + p] : 0.f;
            sX[nl * SXS + p] = f2bf(f);
        }
        for (int idx = tid; idx < 32 * H_DIM; idx += 512) {
            int nl = idx >> 7, k = idx & 127;
            int n = base + nl;
            sH[nl * SHS + k] = f2bf((n < N_NODES) ? hidden[(size_t)n * H_DIM + k] : 0.f);
        }
        float hp[2][4];
        #pragma unroll
        for (int m = 0; m < 2; ++m)
            #pragma unroll
            for (int r = 0; r < 4; ++r) {
                int n = base + m * 16 + quad * 4 + r;
                hp[m][r] = (n < N_NODES) ? hidden[(size_t)n * H_DIM + j] : 0.f;
            }
        __syncthreads();

        for (int t = 0; t < T_STEPS; ++t) {
            #pragma unroll
            for (int m = 0; m < 2; ++m) {
                bf16x8 ax = *(const bf16x8*)&sX[(m * 16 + l16) * SXS + t * 16 + quad * 8];
                if (quad >= 2) {
                    #pragma unroll
                    for (int q = 0; q < 8; ++q) ax[q] = 0;
                }
                f32x4 Cr = __builtin_amdgcn_mfma_f32_16x16x32_bf16(ax, Bih[0], cr0, 0, 0, 0);
                f32x4 Cz = __builtin_amdgcn_mfma_f32_16x16x32_bf16(ax, Bih[1], cz0, 0, 0, 0);
                f32x4 Cn = __builtin_amdgcn_mfma_f32_16x16x32_bf16(ax, Bih[2], cn0, 0, 0, 0);
                f32x4 Ch = ch0;
                #pragma unroll
                for (int kc = 0; kc < 4; ++kc) {
                    bf16x8 ah = *(const bf16x8*)&sH[(m * 16 + l16) * SHS + kc * 32 + quad * 8];
                    Cr = __builtin_amdgcn_mfma_f32_16x16x32_bf16(ah, Bhh[0][kc], Cr, 0, 0, 0);
                    Cz = __builtin_amdgcn_mfma_f32_16x16x32_bf16(ah, Bhh[1][kc], Cz, 0, 0, 0);
                    Ch = __builtin_amdgcn_mfma_f32_16x16x32_bf16(ah, Bhh[2][kc], Ch, 0, 0, 0);
                }
                #pragma unroll
                for (int r = 0; r < 4; ++r) {
                    float rg = sigm(Cr[r]);
                    float zg = sigm(Cz[r]);
                    float ng = tanh_fast(Cn[r] + rg * Ch[r]);
                    hp[m][r] = ng + zg * (hp[m][r] - ng);
                }
            }
            if (t < T_STEPS - 1) {
                __syncthreads();   // all reads of step t done
                #pragma unroll
                for (int m = 0; m < 2; ++m)
                    #pragma unroll
                    for (int r = 0; r < 4; ++r)
                        sH[(m * 16 + quad * 4 + r) * SHS + j] = f2bf(hp[m][r]);
                __syncthreads();   // writes visible for step t+1
            }
        }

        // ---- epilogue: stage h (f32) in LDS; coalesced h_out; fused LN->z ----
        __syncthreads();                       // last step's sX/sH reads done
        float* sF = (float*)sX;                // reuse sX (16 KB needed <= 25.5 KB)
        #pragma unroll
        for (int m = 0; m < 2; ++m)
            #pragma unroll
            for (int r = 0; r < 4; ++r)
                sF[(m * 16 + quad * 4 + r) * 128 + j] = hp[m][r];
        __syncthreads();
        // 32 nodes * 32 float4/node = 1024 float4 total (512 thr * 2 iter)
        #pragma unroll
        for (int it = 0; it < 2; ++it) {
            int idx4 = tid + it * 512;         // float4 index within tile
            int n = base + (idx4 >> 5);        // 32 float4 per node
            if (idx4 < 1024 && n < N_NODES)
                *(float4*)&h_out[(size_t)base * 128 + (size_t)idx4 * 4] =
                    *(const float4*)&sF[idx4 * 4];
        }
        if (zA) {
            #pragma unroll
            for (int i = 0; i < 4; ++i) {
                const int nl = w * 4 + i;      // wave w owns nodes w*4..w*4+3
                const int n = base + nl;
                if (n < N_NODES) {
                    float v0 = sF[nl * 128 + 2 * lane];
                    float v1 = sF[nl * 128 + 2 * lane + 1];
                    float s = v0 + v1, qq = v0 * v0 + v1 * v1;
                    #pragma unroll
                    for (int mm = 32; mm; mm >>= 1) {
                        s  += __shfl_xor(s, mm);
                        qq += __shfl_xor(qq, mm);
                    }
                    float mu  = s * (1.f / H_DIM);
                    float var = fmaxf(qq * (1.f / H_DIM) - mu * mu, 0.f);
                    float inv = rsqrtf(var + LN_EPS);
                    int dg = deg_out[n];
                    float ns = rsqrtf((float)(dg > 0 ? dg : 1));
                    float z0 = (lg2.x * (v0 - mu) * inv + lb2.x) * ns;
                    float z1 = (lg2.y * (v1 - mu) * inv + lb2.y) * ns;
                    zA[(size_t)n * 64 + lane] =
                        ((unsigned int)f2bf(z1) << 16) | (unsigned int)f2bf(z0);
                }
            }
        }
        __syncthreads();
    }
}

// ---------------- per-node LN stats (FALLBACK only, when ws too small for zA) ----------------
__global__ void k_stats(const float* __restrict__ h, const int* __restrict__ deg_out,
                        float4* __restrict__ pqr) {
    int n = blockIdx.x * (blockDim.x >> 6) + (threadIdx.x >> 6);
    int lane = threadIdx.x & 63;
    if (n >= N_NODES) return;
    float v0 = h[(size_t)n * H_DIM + lane];
    float v1 = h[(size_t)n * H_DIM + 64 + lane];
    float s = v0 + v1, qq = v0 * v0 + v1 * v1;
    #pragma unroll
    for (int m = 32; m; m >>= 1) { s += __shfl_xor(s, m); qq += __shfl_xor(qq, m); }
    float mu = s * (1.f / H_DIM);
    float var = fmaxf(qq * (1.f / H_DIM) - mu * mu, 0.f);
    float inv = rsqrtf(var + LN_EPS);
    int d = deg_out[n];
    float ns = rsqrtf((float)(d > 0 ? d : 1));
    if (lane == 0) pqr[n] = make_float4(inv * ns, mu * inv * ns, ns, 0.f);
}

// ---------------- fold Wg into the 4 heads ----------------
__global__ void k_comb(const float* __restrict__ Wg, const float* __restrict__ bg,
                       const float* __restrict__ Wig_mu, const float* __restrict__ big_mu,
                       const float* __restrict__ Wig_std, const float* __restrict__ big_std,
                       const float* __restrict__ Wia_mu, const float* __restrict__ bia_mu,
                       const float* __restrict__ Wia_std, const float* __restrict__ bia_std,
                       unsigned short* __restrict__ Wcomb, float* __restrict__ bcomb) {
    const int r = blockIdx.x;      // 0..255
    const int t = threadIdx.x;     // 0..127 (= k)
    const int rr = r & 63;
    const float* Wh; const float* bh;
    switch (r >> 6) {
        case 0:  Wh = Wig_mu;  bh = big_mu;  break;
        case 1:  Wh = Wig_std; bh = big_std; break;
        case 2:  Wh = Wia_mu;  bh = bia_mu;  break;
        default: Wh = Wia_std; bh = bia_std; break;
    }
    __shared__ float sWr[H_DIM];
    sWr[t] = Wh[(size_t)rr * H_DIM + t];
    __syncthreads();
    const float4* wrow = (const float4*)(Wg + (size_t)t * H_DIM);
    float acc = 0.f;
    #pragma unroll 8
    for (int c4 = 0; c4 < 32; ++c4) {
        float4 v = wrow[c4];
        acc = fmaf(v.x, sWr[4 * c4    ], acc);
        acc = fmaf(v.y, sWr[4 * c4 + 1], acc);
        acc = fmaf(v.z, sWr[4 * c4 + 2], acc);
        acc = fmaf(v.w, sWr[4 * c4 + 3], acc);
    }
    Wcomb[r * H_DIM + t] = f2bf(acc);
    if (t == 0) {
        float s = bh[rr];
        for (int c = 0; c < H_DIM; ++c) s = fmaf(bg[c], sWr[c], s);
        bcomb[r] = s;
    }
}

// ---------------- fused: edge aggregation + MFMA combined-head GEMM ----------------
template<bool USEZ>
__launch_bounds__(256)
__global__ void k_fused(const float* __restrict__ h,
                        const unsigned int* __restrict__ zA,
                        const int* __restrict__ offs, const int* __restrict__ esrc,
                        const float4* __restrict__ pqr,
                        const float* __restrict__ ln_g, const float* __restrict__ ln_b,
                        const unsigned short* __restrict__ Wcomb,
                        const float* __restrict__ bcomb,
                        float* __restrict__ out) {
    __shared__ __align__(16) unsigned short yl[16][136];

    const int tid  = threadIdx.x;
    const int w    = tid >> 6;       // wave 0..3
    const int lane = tid & 63;
    const int l16  = lane & 15;
    const int quad = lane >> 4;
    const long long NI = (long long)N_NODES * I_DIM;

    bf16x8 B[4][4];
    float bc[4];
    #pragma unroll
    for (int ct = 0; ct < 4; ++ct) {
        int col = (w * 4 + ct) * 16 + l16;
        bc[ct] = bcomb[col];
        #pragma unroll
        for (int kc = 0; kc < 4; ++kc)
            B[ct][kc] = *(const bf16x8*)&Wcomb[col * H_DIM + kc * 32 + quad * 8];
    }
    const float2 g2 = *(const float2*)&ln_g[2 * lane];
    const float2 b2 = *(const float2*)&ln_b[2 * lane];

    for (int tile = blockIdx.x; tile < NT16; tile += gridDim.x) {
        const int base = tile * 16;
        #pragma unroll
        for (int i = 0; i < 4; ++i) {
            const int nl = w * 4 + i;
            const int n  = base + nl;
            const int s0 = offs[n], s1 = offs[n + 1];
            float ax = 0.f, ay = 0.f, sq = 0.f, sr = 0.f;
            for (int e0 = s0; e0 < s1; e0 += 64) {
                int sv = (e0 + lane < s1) ? esrc[e0 + lane] : 0;
                const int cnt = min(64, s1 - e0);
                int k = 0;
                if (USEZ) {
                    for (; k + 4 <= cnt; k += 4) {
                        int sa = __shfl(sv, k),     sb = __shfl(sv, k + 1);
                        int sc = __shfl(sv, k + 2), sd = __shfl(sv, k + 3);
                        unsigned int za = zA[(size_t)sa * 64 + lane];
                        unsigned int zb = zA[(size_t)sb * 64 + lane];
                        unsigned int zc = zA[(size_t)sc * 64 + lane];
                        unsigned int zd = zA[(size_t)sd * 64 + lane];
                        float2 fa = bfp(za), fb = bfp(zb), fc = bfp(zc), fd = bfp(zd);
                        ax += (fa.x + fb.x) + (fc.x + fd.x);
                        ay += (fa.y + fb.y) + (fc.y + fd.y);
                    }
                    for (; k < cnt; ++k) {
                        int s = __shfl(sv, k);
                        float2 f = bfp(zA[(size_t)s * 64 + lane]);
                        ax += f.x; ay += f.y;
                    }
                } else {
                    for (; k + 2 <= cnt; k += 2) {
                        int sa = __shfl(sv, k), sb = __shfl(sv, k + 1);
                        float4 Pa = pqr[sa], Pb = pqr[sb];
                        float2 ha = *(const float2*)&h[(size_t)sa * H_DIM + 2 * lane];
                        float2 hb = *(const float2*)&h[(size_t)sb * H_DIM + 2 * lane];
                        ax = fmaf(Pa.x, ha.x, ax); ay = fmaf(Pa.x, ha.y, ay);
                        ax = fmaf(Pb.x, hb.x, ax); ay = fmaf(Pb.x, hb.y, ay);
                        sq += Pa.y + Pb.y; sr += Pa.z + Pb.z;
                    }
                    for (; k < cnt; ++k) {
                        int s = __shfl(sv, k);
                        float4 P = pqr[s];
                        float2 hv = *(const float2*)&h[(size_t)s * H_DIM + 2 * lane];
                        ax = fmaf(P.x, hv.x, ax); ay = fmaf(P.x, hv.y, ay);
                        sq += P.y; sr += P.z;
                    }
                }
            }
            const int d = s1 - s0;
            const float nd = rsqrtf((float)(d > 0 ? d : 1));
            float y0, y1;
            if (USEZ) { y0 = ax * nd; y1 = ay * nd; }
            else {
                y0 = (g2.x * (ax - sq) + b2.x * sr) * nd;
                y1 = (g2.y * (ay - sq) + b2.y * sr) * nd;
            }
            unsigned int pk = ((unsigned int)f2bf(y1) << 16) | (unsigned int)f2bf(y0);
            *(unsigned int*)&yl[nl][2 * lane] = pk;
        }
        __syncthreads();
        bf16x8 A[4];
        #pragma unroll
        for (int kc = 0; kc < 4; ++kc)
            A[kc] = *(const bf16x8*)&yl[l16][kc * 32 + quad * 8];
        #pragma unroll
        for (int ct = 0; ct < 4; ++ct) {
            f32x4 C = {0.f, 0.f, 0.f, 0.f};
            #pragma unroll
            for (int kc = 0; kc < 4; ++kc)
                C = __builtin_amdgcn_mfma_f32_16x16x32_bf16(A[kc], B[ct][kc], C, 0, 0, 0);
            const int col  = (w * 4 + ct) * 16 + l16;
            const int head = col >> 6;
            const int wi   = col & 63;
            const bool sp  = (col & 64) != 0;
            #pragma unroll
            for (int r_ = 0; r_ < 4; ++r_) {
                const int node = base + quad * 4 + r_;
                float v = C[r_] + bc[ct];
                if (sp) v = softplus_f(v);
                out[(long long)head * NI + (long long)node * I_DIM + wi] = v;
            }
        }
        __syncthreads();
    }
}

extern "C" void kernel_launch(void* const* d_in, const int* in_sizes, int n_in,
                              void* d_out, int out_size, void* d_ws, size_t ws_size,
                              hipStream_t stream) {
    const float* actions = (const float*)d_in[0];
    const float* hidden  = (const float*)d_in[1];
    const int*   src     = (const int*)d_in[2];
    const int*   dst     = (const int*)d_in[3];
    const float* W_ih    = (const float*)d_in[4];
    const float* W_hh    = (const float*)d_in[5];
    const float* b_ih    = (const float*)d_in[6];
    const float* b_hh    = (const float*)d_in[7];
    const float* ln_g    = (const float*)d_in[8];
    const float* ln_b    = (const float*)d_in[9];
    const float* Wg      = (const float*)d_in[10];
    const float* bg      = (const float*)d_in[11];
    const float* Wia_mu  = (const float*)d_in[12];
    const float* bia_mu  = (const float*)d_in[13];
    const float* Wia_std = (const float*)d_in[14];
    const float* bia_std = (const float*)d_in[15];
    const float* Wig_mu  = (const float*)d_in[16];
    const float* big_mu  = (const float*)d_in[17];
    const float* Wig_std = (const float*)d_in[18];
    const float* big_std = (const float*)d_in[19];
    float* out = (float*)d_out;

    // ws layout. Base (always): 4,068,928 B. zA path adds 12.8 MB (guarded by
    // ws_size; fallback = pqr path at ~4.87 MB total, known-good).
    char* w = (char*)d_ws;
    const size_t SZN = 200064;
    int*   deg_out = (int*)(w);
    int*   deg_in  = (int*)(w + SZN);
    int*   offs    = (int*)(w + 2 * SZN);            // N+1 ints (200128 slot)
    int*   cursor  = (int*)(w + 2 * SZN + 200128);
    int*   esrc    = (int*)(w + 3 * SZN + 200128);   // 3.2 MB
    char*  p2      = w + 3 * SZN + 200128 + 3200000; // = w + 4,000,320
    int*   bsum    = (int*)(p2);                     // 1024 B slot (196 used)
    int*   boffs   = (int*)(p2 + 1024);              // 1024 B slot
    unsigned short* Wcomb = (unsigned short*)(p2 + 2048);        // 65536
    float* bcomb   = (float*)(p2 + 2048 + 65536);                // 1024
    char*  p3      = p2 + 2048 + 65536 + 1024;       // = w + 4,068,928 (16B aligned)
    float4* pqrA   = (float4*)p3;                    // fallback: 800,000 B
    unsigned int* zA = (unsigned int*)p3;            // z path: 12,800,000 B
    const bool useZ = ws_size >= (size_t)(4068928 + 12800000);

    k_zero<<<2048, 256, 0, stream>>>(deg_out, deg_in, cursor, esrc);
    k_hist<<<1024, 256, 0, stream>>>(src, dst, deg_out, deg_in);
    k_scan1<<<SCB, 256, 0, stream>>>(deg_in, offs, bsum);
    k_scan2<<<1, 256, 0, stream>>>(bsum, boffs, offs);
    k_scan3<<<SCB, 256, 0, stream>>>(boffs, offs);
    k_scatter<<<1024, 256, 0, stream>>>(src, dst, offs, cursor, esrc);
    k_comb<<<256, 128, 0, stream>>>(Wg, bg, Wig_mu, big_mu, Wig_std, big_std,
                                    Wia_mu, bia_mu, Wia_std, bia_std, Wcomb, bcomb);

    // GRU writes f32 h directly into out section 4 (element offset 4*N*I)
    float* h_f = out + (size_t)4 * N_NODES * I_DIM;
    k_gru<<<NT, 512, 0, stream>>>(actions, hidden, W_ih, W_hh, b_ih, b_hh,
                                  ln_g, ln_b, deg_out, useZ ? zA : nullptr, h_f);

    if (useZ) {
        k_fused<true><<<NT16, 256, 0, stream>>>(h_f, zA, offs, esrc, pqrA,
                                                ln_g, ln_b, Wcomb, bcomb, out);
    } else {
        k_stats<<<(N_NODES + 3) / 4, 256, 0, stream>>>(h_f, deg_out, pqrA);
        k_fused<false><<<NT16, 256, 0, stream>>>(h_f, zA, offs, esrc, pqrA,
                                                 ln_g, ln_b, Wcomb, bcomb, out);
    }
}

// Round 9
// 629.770 us; speedup vs baseline: 1.7800x; 1.0121x over previous
//
#include <hip/hip_runtime.h>
#include <hip/hip_bf16.h>
#include <math.h>

constexpr int N_NODES = 50000;
constexpr int T_STEPS = 25;
constexpr int A_DIM   = 16;
constexpr int H_DIM   = 128;
constexpr int G3      = 3 * H_DIM;   // 384
constexpr int E_EDGES = 800000;
constexpr int I_DIM   = 64;
constexpr float LN_EPS = 1e-5f;
constexpr int NT = (N_NODES + 31) / 32;   // 1563 node tiles of 32
constexpr int NT16 = N_NODES / 16;        // 3125 exact (50000 = 16*3125)
constexpr int SXS = 408;                  // sX row stride (elems): 816B, 16B-aligned, 2-way banks
constexpr int SHS = 136;                  // sH row stride (elems): 272B, 2-way banks
constexpr int SCB = 196;                  // scan blocks (196*256 = 50176 >= N)

using bf16x8 = __attribute__((ext_vector_type(8))) short;
using f32x4  = __attribute__((ext_vector_type(4))) float;

static __device__ __forceinline__ float fast_rcp(float x) { return __builtin_amdgcn_rcpf(x); }
static __device__ __forceinline__ float sigm(float x) { return fast_rcp(1.f + __expf(-x)); }
static __device__ __forceinline__ float tanh_fast(float x) {
    return fmaf(2.f, fast_rcp(1.f + __expf(-2.f * x)), -1.f);
}
static __device__ __forceinline__ float softplus_f(float x) {
    return (x > 20.f) ? x : __logf(1.f + __expf(x));
}
static __device__ __forceinline__ unsigned short f2bf(float f) {
    __hip_bfloat16 b = __float2bfloat16(f);   // RNE
    return *(unsigned short*)&b;
}
// decode a uint32 holding two bf16 (low = elem0, high = elem1)
static __device__ __forceinline__ float2 bfp(unsigned int u) {
    union { unsigned int i; float f; } lo, hi;
    lo.i = u << 16; hi.i = u & 0xFFFF0000u;
    return make_float2(lo.f, hi.f);
}

// ---------------- graph preprocessing ----------------

// esrc zeroing removed: every edge has valid dst (randint 0..N), so k_scatter
// fills all offs[N]==E slots — the 3.2MB zero pass was dead work.
__global__ void k_zero(int* deg_out, int* deg_in, int* cursor) {
    for (int i = blockIdx.x * blockDim.x + threadIdx.x; i < N_NODES; i += gridDim.x * blockDim.x) {
        deg_out[i] = 0; deg_in[i] = 0; cursor[i] = 0;
    }
}

__global__ void k_hist(const int* __restrict__ src, const int* __restrict__ dst,
                       int* __restrict__ deg_out, int* __restrict__ deg_in) {
    for (int e = blockIdx.x * blockDim.x + threadIdx.x; e < E_EDGES; e += gridDim.x * blockDim.x) {
        int s = src[e], d = dst[e];
        if (s >= 0 && s < N_NODES) atomicAdd(&deg_out[s], 1);
        if (d >= 0 && d < N_NODES) atomicAdd(&deg_in[d], 1);
    }
}

// 3-kernel parallel scan
__global__ void k_scan1(const int* __restrict__ deg, int* __restrict__ offs,
                        int* __restrict__ bsum) {
    __shared__ int wsum[4];
    const int tid = threadIdx.x, lane = tid & 63, wid = tid >> 6;
    const int i = blockIdx.x * 256 + tid;
    int v = (i < N_NODES) ? deg[i] : 0;
    int x = v;
    #pragma unroll
    for (int off = 1; off < 64; off <<= 1) {
        int yv = __shfl_up(x, off);
        if (lane >= off) x += yv;
    }
    if (lane == 63) wsum[wid] = x;
    __syncthreads();
    int pre = 0;
    #pragma unroll
    for (int w2 = 0; w2 < 3; ++w2) if (w2 < wid) pre += wsum[w2];
    if (i < N_NODES) offs[i] = pre + x - v;   // block-local exclusive
    if (tid == 255) bsum[blockIdx.x] = pre + x;
}

__global__ void k_scan2(const int* __restrict__ bsum, int* __restrict__ boffs,
                        int* __restrict__ offs) {
    __shared__ int wsum[4];
    const int tid = threadIdx.x, lane = tid & 63, wid = tid >> 6;
    int v = (tid < SCB) ? bsum[tid] : 0;
    int x = v;
    #pragma unroll
    for (int off = 1; off < 64; off <<= 1) {
        int yv = __shfl_up(x, off);
        if (lane >= off) x += yv;
    }
    if (lane == 63) wsum[wid] = x;
    __syncthreads();
    int pre = 0;
    #pragma unroll
    for (int w2 = 0; w2 < 3; ++w2) if (w2 < wid) pre += wsum[w2];
    if (tid < SCB) boffs[tid] = pre + x - v;
    if (tid == 255) offs[N_NODES] = pre + x;
}

__global__ void k_scan3(const int* __restrict__ boffs, int* __restrict__ offs) {
    const int i = blockIdx.x * 256 + threadIdx.x;
    if (i < N_NODES) offs[i] += boffs[blockIdx.x];
}

__global__ void k_scatter(const int* __restrict__ src, const int* __restrict__ dst,
                          const int* __restrict__ offs, int* __restrict__ cursor,
                          int* __restrict__ esrc) {
    for (int e = blockIdx.x * blockDim.x + threadIdx.x; e < E_EDGES; e += gridDim.x * blockDim.x) {
        int d = dst[e];
        if (d < 0 || d >= N_NODES) continue;
        int pos = offs[d] + atomicAdd(&cursor[d], 1);
        if (pos >= 0 && pos < E_EDGES) esrc[pos] = src[e];
    }
}

// ---------------- GRU via MFMA ----------------
// Round 9: double-buffered sH -> ONE barrier per step (was 2). At ~3 waves/SIMD
// every barrier drain is exposed; halving barrier count is the cheapest win.
// LDS 43.5KB is also diagnostic for the occupancy cap (regs vs LDS).
__launch_bounds__(512, 4)
__global__ void k_gru(const float* __restrict__ actions,
                      const float* __restrict__ hidden,
                      const float* __restrict__ W_ih,
                      const float* __restrict__ W_hh,
                      const float* __restrict__ b_ih,
                      const float* __restrict__ b_hh,
                      const float* __restrict__ ln_g,
                      const float* __restrict__ ln_b,
                      const int* __restrict__ deg_out,
                      unsigned int* __restrict__ zA,   // null -> skip z fusion
                      float* __restrict__ h_out) {
    __shared__ __align__(16) unsigned short sX[32 * SXS];      // 25.5 KB (reused as f32 staging)
    __shared__ __align__(16) unsigned short sH[2][32 * SHS];   // 17 KB

    const int tid  = threadIdx.x;
    const int w    = tid >> 6;       // 0..7: feature slice
    const int lane = tid & 63;
    const int quad = lane >> 4;
    const int l16  = lane & 15;
    const int j    = 16 * w + l16;   // output feature column, 0..127

    bf16x8 Bhh[3][4];
    #pragma unroll
    for (int gt = 0; gt < 3; ++gt) {
        const float* rowp = W_hh + (size_t)(gt * H_DIM + j) * H_DIM;
        #pragma unroll
        for (int kc = 0; kc < 4; ++kc) {
            const float* p = rowp + kc * 32 + quad * 8;
            float4 f0 = *(const float4*)p;
            float4 f1 = *(const float4*)(p + 4);
            bf16x8 v;
            v[0] = f2bf(f0.x); v[1] = f2bf(f0.y); v[2] = f2bf(f0.z); v[3] = f2bf(f0.w);
            v[4] = f2bf(f1.x); v[5] = f2bf(f1.y); v[6] = f2bf(f1.z); v[7] = f2bf(f1.w);
            Bhh[gt][kc] = v;
        }
    }
    bf16x8 Bih[3];
    #pragma unroll
    for (int gt = 0; gt < 3; ++gt) {
        bf16x8 v;
        #pragma unroll
        for (int q = 0; q < 8; ++q) v[q] = 0;
        if (quad < 2) {
            const float* p = W_ih + (size_t)(gt * H_DIM + j) * A_DIM + quad * 8;
            float4 f0 = *(const float4*)p;
            float4 f1 = *(const float4*)(p + 4);
            v[0] = f2bf(f0.x); v[1] = f2bf(f0.y); v[2] = f2bf(f0.z); v[3] = f2bf(f0.w);
            v[4] = f2bf(f1.x); v[5] = f2bf(f1.y); v[6] = f2bf(f1.z); v[7] = f2bf(f1.w);
        }
        Bih[gt] = v;
    }
    const float br   = b_ih[j] + b_hh[j];
    const float bz   = b_ih[H_DIM + j] + b_hh[H_DIM + j];
    const float bn_i = b_ih[2 * H_DIM + j];
    const float bn_h = b_hh[2 * H_DIM + j];
    const f32x4 cr0 = {br, br, br, br};
    const f32x4 cz0 = {bz, bz, bz, bz};
    const f32x4 cn0 = {bn_i, bn_i, bn_i, bn_i};
    const f32x4 ch0 = {bn_h, bn_h, bn_h, bn_h};
    const float2 lg2 = *(const float2*)&ln_g[2 * lane];
    const float2 lb2 = *(const float2*)&ln_b[2 * lane];

    for (int tile = blockIdx.x; tile < NT; tile += gridDim.x) {
        const int base = tile * 32;
        for (int idx = tid; idx < 32 * SXS; idx += 512) {
            int nl = idx / SXS, p = idx - nl * SXS;
            int n = base + nl;
            float f = (p < 400 && n < N_NODES) ? actions[(size_t)n * 400 + p] : 0.f;
            sX[nl * SXS + p] = f2bf(f);
        }
        for (int idx = tid; idx < 32 * H_DIM; idx += 512) {
            int nl = idx >> 7, k = idx & 127;
            int n = base + nl;
            sH[0][nl * SHS + k] = f2bf((n < N_NODES) ? hidden[(size_t)n * H_DIM + k] : 0.f);
        }
        float hp[2][4];
        #pragma unroll
        for (int m = 0; m < 2; ++m)
            #pragma unroll
            for (int r = 0; r < 4; ++r) {
                int n = base + m * 16 + quad * 4 + r;
                hp[m][r] = (n < N_NODES) ? hidden[(size_t)n * H_DIM + j] : 0.f;
            }
        __syncthreads();

        int cur = 0;
        for (int t = 0; t < T_STEPS; ++t) {
            const int nxt = cur ^ 1;
            #pragma unroll
            for (int m = 0; m < 2; ++m) {
                bf16x8 ax = *(const bf16x8*)&sX[(m * 16 + l16) * SXS + t * 16 + quad * 8];
                if (quad >= 2) {
                    #pragma unroll
                    for (int q = 0; q < 8; ++q) ax[q] = 0;
                }
                f32x4 Cr = __builtin_amdgcn_mfma_f32_16x16x32_bf16(ax, Bih[0], cr0, 0, 0, 0);
                f32x4 Cz = __builtin_amdgcn_mfma_f32_16x16x32_bf16(ax, Bih[1], cz0, 0, 0, 0);
                f32x4 Cn = __builtin_amdgcn_mfma_f32_16x16x32_bf16(ax, Bih[2], cn0, 0, 0, 0);
                f32x4 Ch = ch0;
                #pragma unroll
                for (int kc = 0; kc < 4; ++kc) {
                    bf16x8 ah = *(const bf16x8*)&sH[cur][(m * 16 + l16) * SHS + kc * 32 + quad * 8];
                    Cr = __builtin_amdgcn_mfma_f32_16x16x32_bf16(ah, Bhh[0][kc], Cr, 0, 0, 0);
                    Cz = __builtin_amdgcn_mfma_f32_16x16x32_bf16(ah, Bhh[1][kc], Cz, 0, 0, 0);
                    Ch = __builtin_amdgcn_mfma_f32_16x16x32_bf16(ah, Bhh[2][kc], Ch, 0, 0, 0);
                }
                #pragma unroll
                for (int r = 0; r < 4; ++r) {
                    float rg = sigm(Cr[r]);
                    float zg = sigm(Cz[r]);
                    float ng = tanh_fast(Cn[r] + rg * Ch[r]);
                    float h2 = ng + zg * (hp[m][r] - ng);
                    hp[m][r] = h2;
                    if (t < T_STEPS - 1)
                        sH[nxt][(m * 16 + quad * 4 + r) * SHS + j] = f2bf(h2);
                }
            }
            cur = nxt;
            if (t < T_STEPS - 1) __syncthreads();   // writes to nxt visible; cur-buffer reads all done
        }

        // ---- epilogue: stage h (f32) in LDS; coalesced h_out; fused LN->z ----
        __syncthreads();                       // last step's sX/sH reads done
        float* sF = (float*)sX;                // reuse sX (16 KB needed <= 25.5 KB)
        #pragma unroll
        for (int m = 0; m < 2; ++m)
            #pragma unroll
            for (int r = 0; r < 4; ++r)
                sF[(m * 16 + quad * 4 + r) * 128 + j] = hp[m][r];
        __syncthreads();
        // 32 nodes * 32 float4/node = 1024 float4 total (512 thr * 2 iter)
        #pragma unroll
        for (int it = 0; it < 2; ++it) {
            int idx4 = tid + it * 512;         // float4 index within tile
            int n = base + (idx4 >> 5);        // 32 float4 per node
            if (idx4 < 1024 && n < N_NODES)
                *(float4*)&h_out[(size_t)base * 128 + (size_t)idx4 * 4] =
                    *(const float4*)&sF[idx4 * 4];
        }
        if (zA) {
            #pragma unroll
            for (int i = 0; i < 4; ++i) {
                const int nl = w * 4 + i;      // wave w owns nodes w*4..w*4+3
                const int n = base + nl;
                if (n < N_NODES) {
                    float v0 = sF[nl * 128 + 2 * lane];
                    float v1 = sF[nl * 128 + 2 * lane + 1];
                    float s = v0 + v1, qq = v0 * v0 + v1 * v1;
                    #pragma unroll
                    for (int mm = 32; mm; mm >>= 1) {
                        s  += __shfl_xor(s, mm);
                        qq += __shfl_xor(qq, mm);
                    }
                    float mu  = s * (1.f / H_DIM);
                    float var = fmaxf(qq * (1.f / H_DIM) - mu * mu, 0.f);
                    float inv = rsqrtf(var + LN_EPS);
                    int dg = deg_out[n];
                    float ns = rsqrtf((float)(dg > 0 ? dg : 1));
                    float z0 = (lg2.x * (v0 - mu) * inv + lb2.x) * ns;
                    float z1 = (lg2.y * (v1 - mu) * inv + lb2.y) * ns;
                    zA[(size_t)n * 64 + lane] =
                        ((unsigned int)f2bf(z1) << 16) | (unsigned int)f2bf(z0);
                }
            }
        }
        __syncthreads();
    }
}

// ---------------- per-node LN stats (FALLBACK only, when ws too small for zA) ----------------
__global__ void k_stats(const float* __restrict__ h, const int* __restrict__ deg_out,
                        float4* __restrict__ pqr) {
    int n = blockIdx.x * (blockDim.x >> 6) + (threadIdx.x >> 6);
    int lane = threadIdx.x & 63;
    if (n >= N_NODES) return;
    float v0 = h[(size_t)n * H_DIM + lane];
    float v1 = h[(size_t)n * H_DIM + 64 + lane];
    float s = v0 + v1, qq = v0 * v0 + v1 * v1;
    #pragma unroll
    for (int m = 32; m; m >>= 1) { s += __shfl_xor(s, m); qq += __shfl_xor(qq, m); }
    float mu = s * (1.f / H_DIM);
    float var = fmaxf(qq * (1.f / H_DIM) - mu * mu, 0.f);
    float inv = rsqrtf(var + LN_EPS);
    int d = deg_out[n];
    float ns = rsqrtf((float)(d > 0 ? d : 1));
    if (lane == 0) pqr[n] = make_float4(inv * ns, mu * inv * ns, ns, 0.f);
}

// ---------------- fold Wg into the 4 heads ----------------
__global__ void k_comb(const float* __restrict__ Wg, const float* __restrict__ bg,
                       const float* __restrict__ Wig_mu, const float* __restrict__ big_mu,
                       const float* __restrict__ Wig_std, const float* __restrict__ big_std,
                       const float* __restrict__ Wia_mu, const float* __restrict__ bia_mu,
                       const float* __restrict__ Wia_std, const float* __restrict__ bia_std,
                       unsigned short* __restrict__ Wcomb, float* __restrict__ bcomb) {
    const int r = blockIdx.x;      // 0..255
    const int t = threadIdx.x;     // 0..127 (= k)
    const int rr = r & 63;
    const float* Wh; const float* bh;
    switch (r >> 6) {
        case 0:  Wh = Wig_mu;  bh = big_mu;  break;
        case 1:  Wh = Wig_std; bh = big_std; break;
        case 2:  Wh = Wia_mu;  bh = bia_mu;  break;
        default: Wh = Wia_std; bh = bia_std; break;
    }
    __shared__ float sWr[H_DIM];
    sWr[t] = Wh[(size_t)rr * H_DIM + t];
    __syncthreads();
    const float4* wrow = (const float4*)(Wg + (size_t)t * H_DIM);
    float acc = 0.f;
    #pragma unroll 8
    for (int c4 = 0; c4 < 32; ++c4) {
        float4 v = wrow[c4];
        acc = fmaf(v.x, sWr[4 * c4    ], acc);
        acc = fmaf(v.y, sWr[4 * c4 + 1], acc);
        acc = fmaf(v.z, sWr[4 * c4 + 2], acc);
        acc = fmaf(v.w, sWr[4 * c4 + 3], acc);
    }
    Wcomb[r * H_DIM + t] = f2bf(acc);
    if (t == 0) {
        float s = bh[rr];
        for (int c = 0; c < H_DIM; ++c) s = fmaf(bg[c], sWr[c], s);
        bcomb[r] = s;
    }
}

// ---------------- fused: edge aggregation + MFMA combined-head GEMM ----------------
// zA path: 8-deep unroll (round 9; was 4) — gather is L3-latency-bound, more MLP.
template<bool USEZ>
__launch_bounds__(256)
__global__ void k_fused(const float* __restrict__ h,
                        const unsigned int* __restrict__ zA,
                        const int* __restrict__ offs, const int* __restrict__ esrc,
                        const float4* __restrict__ pqr,
                        const float* __restrict__ ln_g, const float* __restrict__ ln_b,
                        const unsigned short* __restrict__ Wcomb,
                        const float* __restrict__ bcomb,
                        float* __restrict__ out) {
    __shared__ __align__(16) unsigned short yl[16][136];

    const int tid  = threadIdx.x;
    const int w    = tid >> 6;       // wave 0..3
    const int lane = tid & 63;
    const int l16  = lane & 15;
    const int quad = lane >> 4;
    const long long NI = (long long)N_NODES * I_DIM;

    bf16x8 B[4][4];
    float bc[4];
    #pragma unroll
    for (int ct = 0; ct < 4; ++ct) {
        int col = (w * 4 + ct) * 16 + l16;
        bc[ct] = bcomb[col];
        #pragma unroll
        for (int kc = 0; kc < 4; ++kc)
            B[ct][kc] = *(const bf16x8*)&Wcomb[col * H_DIM + kc * 32 + quad * 8];
    }
    const float2 g2 = *(const float2*)&ln_g[2 * lane];
    const float2 b2 = *(const float2*)&ln_b[2 * lane];

    for (int tile = blockIdx.x; tile < NT16; tile += gridDim.x) {
        const int base = tile * 16;
        #pragma unroll
        for (int i = 0; i < 4; ++i) {
            const int nl = w * 4 + i;
            const int n  = base + nl;
            const int s0 = offs[n], s1 = offs[n + 1];
            float ax = 0.f, ay = 0.f, sq = 0.f, sr = 0.f;
            for (int e0 = s0; e0 < s1; e0 += 64) {
                int sv = (e0 + lane < s1) ? esrc[e0 + lane] : 0;
                const int cnt = min(64, s1 - e0);
                int k = 0;
                if (USEZ) {
                    for (; k + 8 <= cnt; k += 8) {
                        int s_[8];
                        #pragma unroll
                        for (int u = 0; u < 8; ++u) s_[u] = __shfl(sv, k + u);
                        unsigned int z_[8];
                        #pragma unroll
                        for (int u = 0; u < 8; ++u) z_[u] = zA[(size_t)s_[u] * 64 + lane];
                        #pragma unroll
                        for (int u = 0; u < 8; ++u) {
                            float2 f = bfp(z_[u]);
                            ax += f.x; ay += f.y;
                        }
                    }
                    for (; k + 4 <= cnt; k += 4) {
                        int sa = __shfl(sv, k),     sb = __shfl(sv, k + 1);
                        int sc = __shfl(sv, k + 2), sd = __shfl(sv, k + 3);
                        unsigned int za = zA[(size_t)sa * 64 + lane];
                        unsigned int zb = zA[(size_t)sb * 64 + lane];
                        unsigned int zc = zA[(size_t)sc * 64 + lane];
                        unsigned int zd = zA[(size_t)sd * 64 + lane];
                        float2 fa = bfp(za), fb = bfp(zb), fc = bfp(zc), fd = bfp(zd);
                        ax += (fa.x + fb.x) + (fc.x + fd.x);
                        ay += (fa.y + fb.y) + (fc.y + fd.y);
                    }
                    for (; k < cnt; ++k) {
                        int s = __shfl(sv, k);
                        float2 f = bfp(zA[(size_t)s * 64 + lane]);
                        ax += f.x; ay += f.y;
                    }
                } else {
                    for (; k + 2 <= cnt; k += 2) {
                        int sa = __shfl(sv, k), sb = __shfl(sv, k + 1);
                        float4 Pa = pqr[sa], Pb = pqr[sb];
                        float2 ha = *(const float2*)&h[(size_t)sa * H_DIM + 2 * lane];
                        float2 hb = *(const float2*)&h[(size_t)sb * H_DIM + 2 * lane];
                        ax = fmaf(Pa.x, ha.x, ax); ay = fmaf(Pa.x, ha.y, ay);
                        ax = fmaf(Pb.x, hb.x, ax); ay = fmaf(Pb.x, hb.y, ay);
                        sq += Pa.y + Pb.y; sr += Pa.z + Pb.z;
                    }
                    for (; k < cnt; ++k) {
                        int s = __shfl(sv, k);
                        float4 P = pqr[s];
                        float2 hv = *(const float2*)&h[(size_t)s * H_DIM + 2 * lane];
                        ax = fmaf(P.x, hv.x, ax); ay = fmaf(P.x, hv.y, ay);
                        sq += P.y; sr += P.z;
                    }
                }
            }
            const int d = s1 - s0;
            const float nd = rsqrtf((float)(d > 0 ? d : 1));
            float y0, y1;
            if (USEZ) { y0 = ax * nd; y1 = ay * nd; }
            else {
                y0 = (g2.x * (ax - sq) + b2.x * sr) * nd;
                y1 = (g2.y * (ay - sq) + b2.y * sr) * nd;
            }
            unsigned int pk = ((unsigned int)f2bf(y1) << 16) | (unsigned int)f2bf(y0);
            *(unsigned int*)&yl[nl][2 * lane] = pk;
        }
        __syncthreads();
        bf16x8 A[4];
        #pragma unroll
        for (int kc = 0; kc < 4; ++kc)
            A[kc] = *(const bf16x8*)&yl[l16][kc * 32 + quad * 8];
        #pragma unroll
        for (int ct = 0; ct < 4; ++ct) {
            f32x4 C = {0.f, 0.f, 0.f, 0.f};
            #pragma unroll
            for (int kc = 0; kc < 4; ++kc)
                C = __builtin_amdgcn_mfma_f32_16x16x32_bf16(A[kc], B[ct][kc], C, 0, 0, 0);
            const int col  = (w * 4 + ct) * 16 + l16;
            const int head = col >> 6;
            const int wi   = col & 63;
            const bool sp  = (col & 64) != 0;
            #pragma unroll
            for (int r_ = 0; r_ < 4; ++r_) {
                const int node = base + quad * 4 + r_;
                float v = C[r_] + bc[ct];
                if (sp) v = softplus_f(v);
                out[(long long)head * NI + (long long)node * I_DIM + wi] = v;
            }
        }
        __syncthreads();
    }
}

extern "C" void kernel_launch(void* const* d_in, const int* in_sizes, int n_in,
                              void* d_out, int out_size, void* d_ws, size_t ws_size,
                              hipStream_t stream) {
    const float* actions = (const float*)d_in[0];
    const float* hidden  = (const float*)d_in[1];
    const int*   src     = (const int*)d_in[2];
    const int*   dst     = (const int*)d_in[3];
    const float* W_ih    = (const float*)d_in[4];
    const float* W_hh    = (const float*)d_in[5];
    const float* b_ih    = (const float*)d_in[6];
    const float* b_hh    = (const float*)d_in[7];
    const float* ln_g    = (const float*)d_in[8];
    const float* ln_b    = (const float*)d_in[9];
    const float* Wg      = (const float*)d_in[10];
    const float* bg      = (const float*)d_in[11];
    const float* Wia_mu  = (const float*)d_in[12];
    const float* bia_mu  = (const float*)d_in[13];
    const float* Wia_std = (const float*)d_in[14];
    const float* bia_std = (const float*)d_in[15];
    const float* Wig_mu  = (const float*)d_in[16];
    const float* big_mu  = (const float*)d_in[17];
    const float* Wig_std = (const float*)d_in[18];
    const float* big_std = (const float*)d_in[19];
    float* out = (float*)d_out;

    // ws layout. Base (always): 4,068,928 B. zA path adds 12.8 MB (guarded by
    // ws_size; fallback = pqr path, known-good).
    char* w = (char*)d_ws;
    const size_t SZN = 200064;
    int*   deg_out = (int*)(w);
    int*   deg_in  = (int*)(w + SZN);
    int*   offs    = (int*)(w + 2 * SZN);            // N+1 ints (200128 slot)
    int*   cursor  = (int*)(w + 2 * SZN + 200128);
    int*   esrc    = (int*)(w + 3 * SZN + 200128);   // 3.2 MB
    char*  p2      = w + 3 * SZN + 200128 + 3200000; // = w + 4,000,320
    int*   bsum    = (int*)(p2);                     // 1024 B slot (196 used)
    int*   boffs   = (int*)(p2 + 1024);              // 1024 B slot
    unsigned short* Wcomb = (unsigned short*)(p2 + 2048);        // 65536
    float* bcomb   = (float*)(p2 + 2048 + 65536);                // 1024
    char*  p3      = p2 + 2048 + 65536 + 1024;       // = w + 4,068,928 (16B aligned)
    float4* pqrA   = (float4*)p3;                    // fallback: 800,000 B
    unsigned int* zA = (unsigned int*)p3;            // z path: 12,800,000 B
    const bool useZ = ws_size >= (size_t)(4068928 + 12800000);

    k_zero<<<256, 256, 0, stream>>>(deg_out, deg_in, cursor);
    k_hist<<<1024, 256, 0, stream>>>(src, dst, deg_out, deg_in);
    k_scan1<<<SCB, 256, 0, stream>>>(deg_in, offs, bsum);
    k_scan2<<<1, 256, 0, stream>>>(bsum, boffs, offs);
    k_scan3<<<SCB, 256, 0, stream>>>(boffs, offs);
    k_scatter<<<1024, 256, 0, stream>>>(src, dst, offs, cursor, esrc);
    k_comb<<<256, 128, 0, stream>>>(Wg, bg, Wig_mu, big_mu, Wig_std, big_std,
                                    Wia_mu, bia_mu, Wia_std, bia_std, Wcomb, bcomb);

    // GRU writes f32 h directly into out section 4 (element offset 4*N*I)
    float* h_f = out + (size_t)4 * N_NODES * I_DIM;
    k_gru<<<NT, 512, 0, stream>>>(actions, hidden, W_ih, W_hh, b_ih, b_hh,
                                  ln_g, ln_b, deg_out, useZ ? zA : nullptr, h_f);

    if (useZ) {
        k_fused<true><<<NT16, 256, 0, stream>>>(h_f, zA, offs, esrc, pqrA,
                                                ln_g, ln_b, Wcomb, bcomb, out);
    } else {
        k_stats<<<(N_NODES + 3) / 4, 256, 0, stream>>>(h_f, deg_out, pqrA);
        k_fused<false><<<NT16, 256, 0, stream>>>(h_f, zA, offs, esrc, pqrA,
                                                 ln_g, ln_b, Wcomb, bcomb, out);
    }
}